// Round 22
// baseline (221.934 us; speedup 1.0000x reference)
//
#include <hip/hip_runtime.h>
#include <hip/hip_bf16.h>
#include <math.h>

typedef __attribute__((ext_vector_type(8))) __bf16 bf16x8;
typedef __attribute__((ext_vector_type(4))) float f32x4;

#define LL 1024
#define DD 1024
#define HH 16

#define GLOAD16(g, l)                                              \
  __builtin_amdgcn_global_load_lds(                                \
      (const __attribute__((address_space(1))) void*)(g),          \
      (__attribute__((address_space(3))) void*)(l), 16, 0, 0)

#define FENCE asm volatile("" ::: "memory")
#define SCHEDB __builtin_amdgcn_sched_barrier(0)
#define BARRIER do { FENCE; __builtin_amdgcn_s_barrier(); FENCE; } while (0)

// ---------------- merged prep: 4 transposes + Er cvt + LN1 in ONE dispatch ----------------
__global__ __launch_bounds__(256) void prep_weights(const float* __restrict__ Wqkv,
                                                    const float* __restrict__ Wproj,
                                                    const float* __restrict__ Wfc,
                                                    const float* __restrict__ Wfc2,
                                                    const float* __restrict__ Er,
                                                    const float* __restrict__ X,
                                                    const float* __restrict__ ln1w,
                                                    const float* __restrict__ ln1b,
                                                    __hip_bfloat16* __restrict__ Wqkvt,
                                                    __hip_bfloat16* __restrict__ Wprojt,
                                                    __hip_bfloat16* __restrict__ Wfct,
                                                    __hip_bfloat16* __restrict__ Wfc2t,
                                                    __hip_bfloat16* __restrict__ Erb,
                                                    __hip_bfloat16* __restrict__ h1) {
  int bid = blockIdx.x;
  int tx = threadIdx.x;
  if (bid >= 12352) {  // ---- LN1 row ----
    int row = bid - 12352;
    const float* xr = X + (size_t)row * DD;
    float4 v = *(const float4*)&xr[tx * 4];
    float s = v.x + v.y + v.z + v.w;
    float s2 = v.x * v.x + v.y * v.y + v.z * v.z + v.w * v.w;
#pragma unroll
    for (int m = 1; m < 64; m <<= 1) {
      s += __shfl_xor(s, m);
      s2 += __shfl_xor(s2, m);
    }
    __shared__ float ps[4], ps2[4];
    int wv_ = tx >> 6, lane = tx & 63;
    if (lane == 0) { ps[wv_] = s; ps2[wv_] = s2; }
    __syncthreads();
    float ts = ps[0] + ps[1] + ps[2] + ps[3];
    float ts2 = ps2[0] + ps2[1] + ps2[2] + ps2[3];
    float mu = ts * (1.0f / DD);
    float var = ts2 * (1.0f / DD) - mu * mu;
    float rs = rsqrtf(var + 1e-5f);
    float4 wv = *(const float4*)&ln1w[tx * 4];
    float4 bv = *(const float4*)&ln1b[tx * 4];
    __hip_bfloat16 o[4];
    o[0] = __float2bfloat16((v.x - mu) * rs * wv.x + bv.x);
    o[1] = __float2bfloat16((v.y - mu) * rs * wv.y + bv.y);
    o[2] = __float2bfloat16((v.z - mu) * rs * wv.z + bv.z);
    o[3] = __float2bfloat16((v.w - mu) * rs * wv.w + bv.w);
    *(uint2*)&h1[(size_t)row * DD + tx * 4] = *(const uint2*)o;
    return;
  }
  if (bid >= 12288) {  // ---- cvt_er ----
    int i = (bid - 12288) * 256 + tx;
    float4 v = *(const float4*)&Er[(size_t)i * 4];
    __hip_bfloat16 o[4];
    o[0] = __float2bfloat16(v.x); o[1] = __float2bfloat16(v.y);
    o[2] = __float2bfloat16(v.z); o[3] = __float2bfloat16(v.w);
    *(uint2*)&Erb[(size_t)i * 4] = *(const uint2*)o;
    return;
  }
  const float* W; __hip_bfloat16* Wt; int R, C, local;
  if (bid < 3072)      { W = Wqkv;  Wt = Wqkvt;  R = 1024; C = 3072; local = bid; }
  else if (bid < 4096) { W = Wproj; Wt = Wprojt; R = 1024; C = 1024; local = bid - 3072; }
  else if (bid < 8192) { W = Wfc;   Wt = Wfct;   R = 1024; C = 4096; local = bid - 4096; }
  else                 { W = Wfc2;  Wt = Wfc2t;  R = 4096; C = 1024; local = bid - 8192; }
  int nbx = C / 32;
  int r0 = (local / nbx) * 32, c0 = (local % nbx) * 32;
  __shared__ float tile[32][33];
  int r = tx >> 3, c4 = (tx & 7) * 4;
  float4 v = *(const float4*)&W[(size_t)(r0 + r) * C + c0 + c4];
  tile[r][c4 + 0] = v.x; tile[r][c4 + 1] = v.y;
  tile[r][c4 + 2] = v.z; tile[r][c4 + 3] = v.w;
  __syncthreads();
  int c = tx >> 3, r4 = (tx & 7) * 4;
  __hip_bfloat16 o[4];
#pragma unroll
  for (int j = 0; j < 4; ++j) o[j] = __float2bfloat16(tile[r4 + j][c]);
  *(uint2*)&Wt[(size_t)(c0 + c) * R + r0 + r4] = *(const uint2*)o;
}

// ---------------- layernorm (fp32 in -> bf16 out) ----------------
__global__ __launch_bounds__(256) void ln_kernel(const float* __restrict__ X,
                                                 const float* __restrict__ w,
                                                 const float* __restrict__ b,
                                                 __hip_bfloat16* __restrict__ out) {
  int row = blockIdx.x;
  int tid = threadIdx.x;
  const float* xr = X + (size_t)row * DD;
  float4 v = *(const float4*)&xr[tid * 4];
  float s = v.x + v.y + v.z + v.w;
  float s2 = v.x * v.x + v.y * v.y + v.z * v.z + v.w * v.w;
#pragma unroll
  for (int m = 1; m < 64; m <<= 1) {
    s += __shfl_xor(s, m);
    s2 += __shfl_xor(s2, m);
  }
  __shared__ float ps[4], ps2[4];
  int wv_ = tid >> 6, lane = tid & 63;
  if (lane == 0) { ps[wv_] = s; ps2[wv_] = s2; }
  __syncthreads();
  float ts = ps[0] + ps[1] + ps[2] + ps[3];
  float ts2 = ps2[0] + ps2[1] + ps2[2] + ps2[3];
  float mu = ts * (1.0f / DD);
  float var = ts2 * (1.0f / DD) - mu * mu;
  float rs = rsqrtf(var + 1e-5f);
  float4 wv = *(const float4*)&w[tid * 4];
  float4 bv = *(const float4*)&b[tid * 4];
  __hip_bfloat16 o[4];
  o[0] = __float2bfloat16((v.x - mu) * rs * wv.x + bv.x);
  o[1] = __float2bfloat16((v.y - mu) * rs * wv.y + bv.y);
  o[2] = __float2bfloat16((v.z - mu) * rs * wv.z + bv.z);
  o[3] = __float2bfloat16((v.w - mu) * rs * wv.w + bv.w);
  *(uint2*)&out[(size_t)row * DD + tid * 4] = *(const uint2*)o;
}

// ===================== 128x128 GEMM, BK=64, double-buffered, 2 blocks/CU (QKV/FC1) =====================
// 8 waves (2M x 4N), per-wave out 64x32. 128B rows -> gloads read 8 full cache lines
// (vs 16 half-lines at BK=32): halves L2 request count per byte (w8's proven layout).
// r16 dbuf schedule: read+MFMA buf[t&1]; barrier; restage freed buf with tile t+2;
// vmcnt(4) -> tile t+1 landed; barrier.
template <int EPI>
__global__ __launch_bounds__(512, 4) void gemm128bk64(const __hip_bfloat16* __restrict__ A,
                                                      const __hip_bfloat16* __restrict__ Bt,
                                                      const float* __restrict__ bias,
                                                      const float* __restrict__ resid,
                                                      void* __restrict__ Cout,
                                                      int M, int N, int K) {
  __shared__ __hip_bfloat16 Ab[2][128][64];  // 2 x 16 KB
  __shared__ __hip_bfloat16 Bb[2][128][64];  // 2 x 16 KB
  const int tid = threadIdx.x, lane = tid & 63, w = tid >> 6;
  const int wm = w >> 2, wn = w & 3;  // 2M x 4N waves

  int nbx = gridDim.x, nwg = nbx * gridDim.y;
  int orig = blockIdx.y * nbx + blockIdx.x;
  int cpx = nwg >> 3;
  int wgid = (orig & 7) * cpx + (orig >> 3);  // grids %8==0
  int bm0 = (wgid / nbx) * 128, bn0 = (wgid % nbx) * 128;

  const int fr = lane & 15, kq = lane >> 4;
  const int srw = lane >> 3;                      // row within 8-row unit
  const int sg = ((lane & 7) ^ (lane >> 3)) * 8;  // inverse-swizzled src col (elems)

  // 16 A units + 16 B units of 8rows x 128B per K64-step; wave w stages 2 of each
  auto stageA = [&](int c, int j, int k0) {
    int u = 2 * w + j;  // 0..15
    const __hip_bfloat16* src = A + (size_t)(bm0 + u * 8 + srw) * K + k0 + sg;
    GLOAD16(src, (char*)Ab + c * 16384 + u * 1024);
  };
  auto stageB = [&](int c, int j, int k0) {
    int u = 2 * w + j;
    const __hip_bfloat16* src = Bt + (size_t)(bn0 + u * 8 + srw) * K + k0 + sg;
    GLOAD16(src, (char*)Bb + c * 16384 + u * 1024);
  };
  auto ldA = [&](int c, int r, int ks) -> bf16x8 {
    int byte = r * 128 + ((ks * 64 + kq * 16) ^ ((r & 7) << 4));
    return *(const bf16x8*)((const char*)Ab + c * 16384 + byte);
  };
  auto ldB = [&](int c, int r, int ks) -> bf16x8 {
    int byte = r * 128 + ((ks * 64 + kq * 16) ^ ((r & 7) << 4));
    return *(const bf16x8*)((const char*)Bb + c * 16384 + byte);
  };

  f32x4 acc[4][2] = {};
  bf16x8 a[4][2], b[2][2];

  const int nt = K >> 6;
  // prologue: tile0 -> buf0, tile1 -> buf1 (8 gloads/wave); vmcnt(4) -> tile0 landed
  stageA(0, 0, 0);  stageA(0, 1, 0);  stageB(0, 0, 0);  stageB(0, 1, 0);
  stageA(1, 0, 64); stageA(1, 1, 64); stageB(1, 0, 64); stageB(1, 1, 64);
  asm volatile("s_waitcnt vmcnt(4)" ::: "memory");
  BARRIER;

  for (int t = 0; t < nt; ++t) {
    const int cur = t & 1;
#pragma unroll
    for (int mf = 0; mf < 4; ++mf)
#pragma unroll
      for (int ks = 0; ks < 2; ++ks)
        a[mf][ks] = ldA(cur, wm * 64 + mf * 16 + fr, ks);
#pragma unroll
    for (int nf = 0; nf < 2; ++nf)
#pragma unroll
      for (int ks = 0; ks < 2; ++ks)
        b[nf][ks] = ldB(cur, wn * 32 + nf * 16 + fr, ks);
    __builtin_amdgcn_s_setprio(1);
#pragma unroll
    for (int mf = 0; mf < 4; ++mf)
#pragma unroll
      for (int nf = 0; nf < 2; ++nf)
#pragma unroll
        for (int ks = 0; ks < 2; ++ks)
          acc[mf][nf] = __builtin_amdgcn_mfma_f32_16x16x32_bf16(
              a[mf][ks], b[nf][ks], acc[mf][nf], 0, 0, 0);
    __builtin_amdgcn_s_setprio(0);
    BARRIER;  // all waves done reading buf[cur] (frags consumed by MFMA)
    if (t + 2 < nt) {  // re-stage freed buffer with tile t+2
      int kn = (t + 2) * 64;
      stageA(cur, 0, kn); stageA(cur, 1, kn); stageB(cur, 0, kn); stageB(cur, 1, kn);
      asm volatile("s_waitcnt vmcnt(4)" ::: "memory");  // tile t+1 landed
    } else if (t + 1 < nt) {
      asm volatile("s_waitcnt vmcnt(0)" ::: "memory");
    }
    BARRIER;  // publish tile t+1
  }

  // epilogue: wave (wm,wn) owns 64x32 at (bm0+wm*64, bn0+wn*32)
#pragma unroll
  for (int nf = 0; nf < 2; ++nf) {
    int col = bn0 + wn * 32 + nf * 16 + fr;
    float bsv = bias[col];
#pragma unroll
    for (int mf = 0; mf < 4; ++mf) {
      int rowb = bm0 + wm * 64 + mf * 16 + kq * 4;
#pragma unroll
      for (int j = 0; j < 4; ++j) {
        int row = rowb + j;
        float v = acc[mf][nf][j] + bsv;
        if (EPI == 1) v = 0.5f * v * (1.0f + erff(v * 0.7071067811865476f));
        if (EPI == 2) {
          ((float*)Cout)[(size_t)row * N + col] = v + resid[(size_t)row * N + col];
        } else {
          ((__hip_bfloat16*)Cout)[(size_t)row * N + col] = __float2bfloat16(v);
        }
      }
    }
  }
}

// ===================== 128x64 GEMM, 8 waves, BK=64, triple-buffered (proj/FC2) =====================
template <int EPI>
__global__ __launch_bounds__(512, 4) void gemm128x64w8(const __hip_bfloat16* __restrict__ A,
                                                       const __hip_bfloat16* __restrict__ Bt,
                                                       const float* __restrict__ bias,
                                                       const float* __restrict__ resid,
                                                       void* __restrict__ Cout,
                                                       int M, int N, int K) {
  __shared__ __hip_bfloat16 Ab[3][128][64];  // 3 x 16 KB
  __shared__ __hip_bfloat16 Bb[3][64][64];   // 3 x 8 KB
  const int tid = threadIdx.x, lane = tid & 63, w = tid >> 6;
  const int wm = w >> 1, wn = w & 1;

  int nbx = gridDim.x, nwg = nbx * gridDim.y;
  int orig = blockIdx.y * nbx + blockIdx.x;
  int cpx = nwg >> 3;
  int wgid = (orig & 7) * cpx + (orig >> 3);
  int bm0 = (wgid / nbx) * 128, bn0 = (wgid % nbx) * 64;

  const int fr = lane & 15, kq = lane >> 4;
  const int srw = lane >> 3;
  const int sg = ((lane & 7) ^ (lane >> 3)) * 8;

  auto stageA = [&](int c, int j, int k0) {
    int u = 2 * w + j;
    const __hip_bfloat16* src = A + (size_t)(bm0 + u * 8 + srw) * K + k0 + sg;
    GLOAD16(src, (char*)Ab + c * 16384 + u * 1024);
  };
  auto stageB = [&](int c, int k0) {
    const __hip_bfloat16* src = Bt + (size_t)(bn0 + w * 8 + srw) * K + k0 + sg;
    GLOAD16(src, (char*)Bb + c * 8192 + w * 1024);
  };
  auto ldA = [&](int c, int r, int ks) -> bf16x8 {
    int byte = r * 128 + ((ks * 64 + kq * 16) ^ ((r & 7) << 4));
    return *(const bf16x8*)((const char*)Ab + c * 16384 + byte);
  };
  auto ldB = [&](int c, int r, int ks) -> bf16x8 {
    int byte = r * 128 + ((ks * 64 + kq * 16) ^ ((r & 7) << 4));
    return *(const bf16x8*)((const char*)Bb + c * 8192 + byte);
  };

  f32x4 acc[2][2] = {};
  bf16x8 a[2][2], b[2][2];

  const int nt = K >> 6;
#pragma unroll
  for (int tt = 0; tt < 2; ++tt) {
    stageA(tt, 0, tt * 64); stageA(tt, 1, tt * 64); stageB(tt, tt * 64);
  }
  asm volatile("s_waitcnt vmcnt(3)" ::: "memory");
  BARRIER;

  int cur = 0, nxt = 2;
  for (int t = 0; t < nt; ++t) {
#pragma unroll
    for (int mf = 0; mf < 2; ++mf)
#pragma unroll
      for (int ks = 0; ks < 2; ++ks)
        a[mf][ks] = ldA(cur, wm * 32 + mf * 16 + fr, ks);
#pragma unroll
    for (int nf = 0; nf < 2; ++nf)
#pragma unroll
      for (int ks = 0; ks < 2; ++ks)
        b[nf][ks] = ldB(cur, wn * 32 + nf * 16 + fr, ks);
    if (t + 2 < nt) {
      stageA(nxt, 0, (t + 2) * 64); stageA(nxt, 1, (t + 2) * 64); stageB(nxt, (t + 2) * 64);
    }
    __builtin_amdgcn_s_setprio(1);
#pragma unroll
    for (int mf = 0; mf < 2; ++mf)
#pragma unroll
      for (int nf = 0; nf < 2; ++nf)
#pragma unroll
        for (int ks = 0; ks < 2; ++ks)
          acc[mf][nf] = __builtin_amdgcn_mfma_f32_16x16x32_bf16(
              a[mf][ks], b[nf][ks], acc[mf][nf], 0, 0, 0);
    __builtin_amdgcn_s_setprio(0);
    if (t <= nt - 3)      { asm volatile("s_waitcnt vmcnt(3)" ::: "memory"); }
    else if (t == nt - 2) { asm volatile("s_waitcnt vmcnt(0)" ::: "memory"); }
    BARRIER;
    cur = (cur == 2) ? 0 : cur + 1;
    nxt = (nxt == 2) ? 0 : nxt + 1;
  }

#pragma unroll
  for (int nf = 0; nf < 2; ++nf) {
    int col = bn0 + wn * 32 + nf * 16 + fr;
    float bsv = bias[col];
#pragma unroll
    for (int mf = 0; mf < 2; ++mf) {
      int rowb = bm0 + wm * 32 + mf * 16 + kq * 4;
#pragma unroll
      for (int j = 0; j < 4; ++j) {
        int row = rowb + j;
        float v = acc[mf][nf][j] + bsv;
        if (EPI == 1) v = 0.5f * v * (1.0f + erff(v * 0.7071067811865476f));
        if (EPI == 2) {
          ((float*)Cout)[(size_t)row * N + col] = v + resid[(size_t)row * N + col];
        } else {
          ((__hip_bfloat16*)Cout)[(size_t)row * N + col] = __float2bfloat16(v);
        }
      }
    }
  }
}

// ---------------- MFMA flash attention, defer-max (unchanged) ----------------
__global__ __launch_bounds__(256) void attn_mfma(const __hip_bfloat16* __restrict__ qkv,
                                                 const __hip_bfloat16* __restrict__ Erb,
                                                 __hip_bfloat16* __restrict__ Y) {
  __shared__ __hip_bfloat16 k_s[64][72];
  __shared__ __hip_bfloat16 er_s[64][72];
  __shared__ __hip_bfloat16 p_s[4][16][72];
  __shared__ __hip_bfloat16 g_s[4][16][132];
  __shared__ __hip_bfloat16 vt_s[64 * 64];

  int bid = blockIdx.x;
  int qi = 15 - (bid >> 6);
  int head = bid & 63;
  int h = head & 15, b = head >> 4;
  int l0 = qi * 64;
  int tid = threadIdx.x, lane = tid & 63, w = tid >> 6;
  const int fr = lane & 15, kq = lane >> 4;

  const __hip_bfloat16* base = qkv + (size_t)b * (LL * 3072) + h * 64;

  bf16x8 qf[2];
  {
    const __hip_bfloat16* q0 = base + (size_t)(l0 + 16 * w + fr) * 3072 + kq * 8;
    qf[0] = *(const bf16x8*)q0;
    qf[1] = *(const bf16x8*)(q0 + 32);
  }

  const int ksr = tid >> 2, ksd = (tid & 3) * 16;
  const __hip_bfloat16* ksrc = base + 1024 + (size_t)ksr * 3072 + ksd;
  const int vc = (tid >> 3) * 2, vd0 = (tid & 7) * 8;
  const __hip_bfloat16* vsrc = base + 2048 + (size_t)vc * 3072 + vd0;
  const int err = tid >> 2, erc = (tid & 3) * 16;

  uint4 kst0, kst1, vst0, vst1;
  uint4 ers0, ers1;
  uint4 ec10, ec11;

  {
    kst0 = *(const uint4*)ksrc; kst1 = *(const uint4*)(ksrc + 8);
    vst0 = *(const uint4*)vsrc; vst1 = *(const uint4*)(vsrc + 3072);
    int m0 = min(max(960 - l0 + err, 0), 1023);
    const __hip_bfloat16* ep0 = Erb + (size_t)m0 * 64 + erc;
    ers0 = *(const uint4*)ep0; ers1 = *(const uint4*)(ep0 + 8);
    if (qi > 0) {
      int m1 = min(max(960 - l0 + 64 + err, 0), 1023);
      const __hip_bfloat16* ep1 = Erb + (size_t)m1 * 64 + erc;
      ec10 = *(const uint4*)ep1; ec11 = *(const uint4*)(ep1 + 8);
    }
  }

  f32x4 oacc[4] = {};
  float m_run[4], s_run[4];
#pragma unroll
  for (int j = 0; j < 4; ++j) { m_run[j] = -1e30f; s_run[j] = 0.f; }

  auto gchunk = [&](int hf) {
#pragma unroll
    for (int g = 0; g < 4; ++g) {
      int cc = 16 * g + fr, kc = kq * 8;
      bf16x8 e0 = *(const bf16x8*)&er_s[cc][kc];
      bf16x8 e1 = *(const bf16x8*)&er_s[cc][kc + 32];
      f32x4 gacc = {};
      gacc = __builtin_amdgcn_mfma_f32_16x16x32_bf16(qf[0], e0, gacc, 0, 0, 0);
      gacc = __builtin_amdgcn_mfma_f32_16x16x32_bf16(qf[1], e1, gacc, 0, 0, 0);
#pragma unroll
      for (int j = 0; j < 4; ++j)
        g_s[w][kq * 4 + j][hf * 64 + 16 * g + fr] = __float2bfloat16(gacc[j]);
    }
  };

  for (int t = 0; t <= qi; ++t) {
    __syncthreads();
    *(uint4*)&k_s[ksr][ksd] = kst0;
    *(uint4*)&k_s[ksr][ksd + 8] = kst1;
    {
      const uint16_t* h0 = (const uint16_t*)&vst0;
      const uint16_t* h1 = (const uint16_t*)&vst1;
#pragma unroll
      for (int j = 0; j < 8; ++j) {
        int d = vd0 + j;
        uint32_t pk = (uint32_t)h0[j] | ((uint32_t)h1[j] << 16);
        uint32_t byte = ((uint32_t)d << 7) + 2u * (uint32_t)vc;
        byte ^= (uint32_t)(((d & 7) ^ (d >> 3)) << 4);
        *(uint32_t*)((char*)vt_s + byte) = pk;
      }
    }
    if (t == 0 || t < qi) {
      *(uint4*)&er_s[err][erc]     = ers0;
      *(uint4*)&er_s[err][erc + 8] = ers1;
    }
    __syncthreads();
    if (t < qi) {
      int c0n = (t + 1) * 64;
      const __hip_bfloat16* kp = ksrc + (size_t)c0n * 3072;
      kst0 = *(const uint4*)kp; kst1 = *(const uint4*)(kp + 8);
      const __hip_bfloat16* vp = vsrc + (size_t)c0n * 3072;
      vst0 = *(const uint4*)vp; vst1 = *(const uint4*)(vp + 3072);
      if (t + 1 < qi) {
        int m = min(960 - l0 + (t + 2) * 64 + err, 1023);
        const __hip_bfloat16* ep = Erb + (size_t)m * 64 + erc;
        ers0 = *(const uint4*)ep; ers1 = *(const uint4*)(ep + 8);
      }
    }
    SCHEDB;

    f32x4 sacc[4] = {};
#pragma unroll
    for (int f = 0; f < 4; ++f) {
      int cc = 16 * f + fr, kc = kq * 8;
      bf16x8 k0 = *(const bf16x8*)&k_s[cc][kc];
      bf16x8 k1 = *(const bf16x8*)&k_s[cc][kc + 32];
      sacc[f] = __builtin_amdgcn_mfma_f32_16x16x32_bf16(qf[0], k0, sacc[f], 0, 0, 0);
      sacc[f] = __builtin_amdgcn_mfma_f32_16x16x32_bf16(qf[1], k1, sacc[f], 0, 0, 0);
    }
    if (t == 0) {
      gchunk(0);
      if (qi > 0) {
        __syncthreads();
        *(uint4*)&er_s[err][erc]     = ec10;
        *(uint4*)&er_s[err][erc + 8] = ec11;
        __syncthreads();
        gchunk(1);
      }
    } else if (t < qi) {
      gchunk((t + 1) & 1);
    }

    float sv[4][4];
#pragma unroll
    for (int f = 0; f < 4; ++f) {
#pragma unroll
      for (int j = 0; j < 4; ++j) {
        int r = kq * 4 + j;
        int c = 16 * f + fr;
        int jj = c - (16 * w + r) + 63;
        float g = __bfloat162float(g_s[w][r][(t * 64 + jj) & 127]);
        float val = (sacc[f][j] + g) * 0.125f;
        if (t == qi && c > 16 * w + r) val = -1e30f;
        sv[f][j] = val;
      }
    }
    float tm[4];
#pragma unroll
    for (int j = 0; j < 4; ++j) {
      float m_ = fmaxf(fmaxf(sv[0][j], sv[1][j]), fmaxf(sv[2][j], sv[3][j]));
      m_ = fmaxf(m_, __shfl_xor(m_, 1));
      m_ = fmaxf(m_, __shfl_xor(m_, 2));
      m_ = fmaxf(m_, __shfl_xor(m_, 4));
      m_ = fmaxf(m_, __shfl_xor(m_, 8));
      tm[j] = m_;
    }
    bool need = (tm[0] > m_run[0] + 8.f) || (tm[1] > m_run[1] + 8.f) ||
                (tm[2] > m_run[2] + 8.f) || (tm[3] > m_run[3] + 8.f);
    float alpha[4];
    if (need) {
#pragma unroll
      for (int j = 0; j < 4; ++j) {
        float nm = fmaxf(m_run[j], tm[j]);
        alpha[j] = __expf(m_run[j] - nm);
        m_run[j] = nm;
      }
    }
#pragma unroll
    for (int f = 0; f < 4; ++f)
#pragma unroll
      for (int j = 0; j < 4; ++j)
        sv[f][j] = __expf(sv[f][j] - m_run[j]);
#pragma unroll
    for (int j = 0; j < 4; ++j) {
      float ps = sv[0][j] + sv[1][j] + sv[2][j] + sv[3][j];
      ps += __shfl_xor(ps, 1); ps += __shfl_xor(ps, 2);
      ps += __shfl_xor(ps, 4); ps += __shfl_xor(ps, 8);
      s_run[j] = (need ? s_run[j] * alpha[j] : s_run[j]) + ps;
    }
    if (need) {
#pragma unroll
      for (int f = 0; f < 4; ++f)
#pragma unroll
        for (int j = 0; j < 4; ++j)
          oacc[f][j] *= alpha[j];
    }
#pragma unroll
    for (int f = 0; f < 4; ++f)
#pragma unroll
      for (int j = 0; j < 4; ++j)
        p_s[w][kq * 4 + j][16 * f + fr] = __float2bfloat16(sv[f][j]);
#pragma unroll
    for (int kk = 0; kk < 2; ++kk) {
      bf16x8 pf = *(const bf16x8*)&p_s[w][fr][kq * 8 + 32 * kk];
#pragma unroll
      for (int f = 0; f < 4; ++f) {
        int d = 16 * f + fr;
        int cc = kq * 8 + 32 * kk;
        uint32_t byte = ((uint32_t)d << 7) + 2u * (uint32_t)cc;
        byte ^= (uint32_t)(((d & 7) ^ (d >> 3)) << 4);
        bf16x8 vf = *(const bf16x8*)((char*)vt_s + byte);
        oacc[f] = __builtin_amdgcn_mfma_f32_16x16x32_bf16(pf, vf, oacc[f], 0, 0, 0);
      }
    }
  }

#pragma unroll
  for (int f = 0; f < 4; ++f)
#pragma unroll
    for (int j = 0; j < 4; ++j) {
      int r = 16 * w + kq * 4 + j;
      int d = 16 * f + fr;
      float o = oacc[f][j] / s_run[j];
      Y[(size_t)(b * LL + l0 + r) * DD + h * 64 + d] = __float2bfloat16(o);
    }
}

// ---------------- launch ----------------
extern "C" void kernel_launch(void* const* d_in, const int* in_sizes, int n_in,
                              void* d_out, int out_size, void* d_ws, size_t ws_size,
                              hipStream_t stream) {
  (void)in_sizes; (void)n_in; (void)out_size; (void)ws_size;
  const float* x     = (const float*)d_in[0];
  const float* ln1w  = (const float*)d_in[1];
  const float* ln1b  = (const float*)d_in[2];
  const float* Wqkv  = (const float*)d_in[3];
  const float* bqkv  = (const float*)d_in[4];
  const float* Wproj = (const float*)d_in[5];
  const float* bproj = (const float*)d_in[6];
  const float* Er    = (const float*)d_in[7];
  const float* ln2w  = (const float*)d_in[8];
  const float* ln2b  = (const float*)d_in[9];
  const float* Wfc   = (const float*)d_in[10];
  const float* bfc   = (const float*)d_in[11];
  const float* Wfc2  = (const float*)d_in[12];
  const float* bfc2  = (const float*)d_in[13];
  float* out = (float*)d_out;

  char* ws = (char*)d_ws;
  const size_t MB = 1ull << 20;
  __hip_bfloat16* h1    = (__hip_bfloat16*)(ws + 0);        // 8 MB
  __hip_bfloat16* qkvb  = (__hip_bfloat16*)(ws + 8 * MB);   // 24 MB
  __hip_bfloat16* mbuf  = (__hip_bfloat16*)(ws + 0);        // 32 MB (aliases h1+qkvb)
  __hip_bfloat16* yb    = (__hip_bfloat16*)(ws + 32 * MB);  // 8 MB
  __hip_bfloat16* h2    = (__hip_bfloat16*)(ws + 32 * MB);  // 8 MB (aliases yb)
  float*          x2    = (float*)(ws + 40 * MB);           // 16 MB
  __hip_bfloat16* Wqkvt = (__hip_bfloat16*)(ws + 56 * MB);  // 6 MB
  __hip_bfloat16* Erb   = (__hip_bfloat16*)(ws + 62 * MB);  // 128 KB
  __hip_bfloat16* Wprojt= (__hip_bfloat16*)(ws + 63 * MB);  // 2 MB
  __hip_bfloat16* Wfct  = (__hip_bfloat16*)(ws + 66 * MB);  // 8 MB
  __hip_bfloat16* Wfc2t = (__hip_bfloat16*)(ws + 75 * MB);  // 8 MB

  dim3 blk(256);

  prep_weights<<<dim3(16448), blk, 0, stream>>>(Wqkv, Wproj, Wfc, Wfc2, Er,
                                                x, ln1w, ln1b,
                                                Wqkvt, Wprojt, Wfct, Wfc2t, Erb, h1);

  gemm128bk64<0><<<dim3(3072 / 128, 4096 / 128), dim3(512), 0, stream>>>(
      h1, Wqkvt, bqkv, nullptr, qkvb, 4096, 3072, 1024);

  attn_mfma<<<dim3(1024), blk, 0, stream>>>(qkvb, Erb, yb);

  gemm128x64w8<2><<<dim3(1024 / 64, 4096 / 128), dim3(512), 0, stream>>>(
      yb, Wprojt, bproj, x, x2, 4096, 1024, 1024);

  ln_kernel<<<4096, blk, 0, stream>>>(x2, ln2w, ln2b, h2);

  gemm128bk64<1><<<dim3(4096 / 128, 4096 / 128), dim3(512), 0, stream>>>(
      h2, Wfct, bfc, nullptr, mbuf, 4096, 4096, 1024);

  gemm128x64w8<2><<<dim3(1024 / 64, 4096 / 128), dim3(512), 0, stream>>>(
      mbuf, Wfc2t, bfc2, x2, out, 4096, 1024, 4096);
}

// Round 23
// 219.447 us; speedup vs baseline: 1.0113x; 1.0113x over previous
//
#include <hip/hip_runtime.h>
#include <hip/hip_bf16.h>
#include <math.h>

typedef __attribute__((ext_vector_type(8))) __bf16 bf16x8;
typedef __attribute__((ext_vector_type(4))) float f32x4;

#define LL 1024
#define DD 1024
#define HH 16

#define GLOAD16(g, l)                                              \
  __builtin_amdgcn_global_load_lds(                                \
      (const __attribute__((address_space(1))) void*)(g),          \
      (__attribute__((address_space(3))) void*)(l), 16, 0, 0)

#define FENCE asm volatile("" ::: "memory")
#define SCHEDB __builtin_amdgcn_sched_barrier(0)
#define BARRIER do { FENCE; __builtin_amdgcn_s_barrier(); FENCE; } while (0)

// ---------------- merged prep: 4 transposes + Er cvt + LN1 in ONE dispatch ----------------
__global__ __launch_bounds__(256) void prep_weights(const float* __restrict__ Wqkv,
                                                    const float* __restrict__ Wproj,
                                                    const float* __restrict__ Wfc,
                                                    const float* __restrict__ Wfc2,
                                                    const float* __restrict__ Er,
                                                    const float* __restrict__ X,
                                                    const float* __restrict__ ln1w,
                                                    const float* __restrict__ ln1b,
                                                    __hip_bfloat16* __restrict__ Wqkvt,
                                                    __hip_bfloat16* __restrict__ Wprojt,
                                                    __hip_bfloat16* __restrict__ Wfct,
                                                    __hip_bfloat16* __restrict__ Wfc2t,
                                                    __hip_bfloat16* __restrict__ Erb,
                                                    __hip_bfloat16* __restrict__ h1) {
  int bid = blockIdx.x;
  int tx = threadIdx.x;
  if (bid >= 12352) {  // ---- LN1 row ----
    int row = bid - 12352;
    const float* xr = X + (size_t)row * DD;
    float4 v = *(const float4*)&xr[tx * 4];
    float s = v.x + v.y + v.z + v.w;
    float s2 = v.x * v.x + v.y * v.y + v.z * v.z + v.w * v.w;
#pragma unroll
    for (int m = 1; m < 64; m <<= 1) {
      s += __shfl_xor(s, m);
      s2 += __shfl_xor(s2, m);
    }
    __shared__ float ps[4], ps2[4];
    int wv_ = tx >> 6, lane = tx & 63;
    if (lane == 0) { ps[wv_] = s; ps2[wv_] = s2; }
    __syncthreads();
    float ts = ps[0] + ps[1] + ps[2] + ps[3];
    float ts2 = ps2[0] + ps2[1] + ps2[2] + ps2[3];
    float mu = ts * (1.0f / DD);
    float var = ts2 * (1.0f / DD) - mu * mu;
    float rs = rsqrtf(var + 1e-5f);
    float4 wv = *(const float4*)&ln1w[tx * 4];
    float4 bv = *(const float4*)&ln1b[tx * 4];
    __hip_bfloat16 o[4];
    o[0] = __float2bfloat16((v.x - mu) * rs * wv.x + bv.x);
    o[1] = __float2bfloat16((v.y - mu) * rs * wv.y + bv.y);
    o[2] = __float2bfloat16((v.z - mu) * rs * wv.z + bv.z);
    o[3] = __float2bfloat16((v.w - mu) * rs * wv.w + bv.w);
    *(uint2*)&h1[(size_t)row * DD + tx * 4] = *(const uint2*)o;
    return;
  }
  if (bid >= 12288) {  // ---- cvt_er ----
    int i = (bid - 12288) * 256 + tx;
    float4 v = *(const float4*)&Er[(size_t)i * 4];
    __hip_bfloat16 o[4];
    o[0] = __float2bfloat16(v.x); o[1] = __float2bfloat16(v.y);
    o[2] = __float2bfloat16(v.z); o[3] = __float2bfloat16(v.w);
    *(uint2*)&Erb[(size_t)i * 4] = *(const uint2*)o;
    return;
  }
  const float* W; __hip_bfloat16* Wt; int R, C, local;
  if (bid < 3072)      { W = Wqkv;  Wt = Wqkvt;  R = 1024; C = 3072; local = bid; }
  else if (bid < 4096) { W = Wproj; Wt = Wprojt; R = 1024; C = 1024; local = bid - 3072; }
  else if (bid < 8192) { W = Wfc;   Wt = Wfct;   R = 1024; C = 4096; local = bid - 4096; }
  else                 { W = Wfc2;  Wt = Wfc2t;  R = 4096; C = 1024; local = bid - 8192; }
  int nbx = C / 32;
  int r0 = (local / nbx) * 32, c0 = (local % nbx) * 32;
  __shared__ float tile[32][33];
  int r = tx >> 3, c4 = (tx & 7) * 4;
  float4 v = *(const float4*)&W[(size_t)(r0 + r) * C + c0 + c4];
  tile[r][c4 + 0] = v.x; tile[r][c4 + 1] = v.y;
  tile[r][c4 + 2] = v.z; tile[r][c4 + 3] = v.w;
  __syncthreads();
  int c = tx >> 3, r4 = (tx & 7) * 4;
  __hip_bfloat16 o[4];
#pragma unroll
  for (int j = 0; j < 4; ++j) o[j] = __float2bfloat16(tile[r4 + j][c]);
  *(uint2*)&Wt[(size_t)(c0 + c) * R + r0 + r4] = *(const uint2*)o;
}

// ---------------- layernorm (fp32 in -> bf16 out) ----------------
__global__ __launch_bounds__(256) void ln_kernel(const float* __restrict__ X,
                                                 const float* __restrict__ w,
                                                 const float* __restrict__ b,
                                                 __hip_bfloat16* __restrict__ out) {
  int row = blockIdx.x;
  int tid = threadIdx.x;
  const float* xr = X + (size_t)row * DD;
  float4 v = *(const float4*)&xr[tid * 4];
  float s = v.x + v.y + v.z + v.w;
  float s2 = v.x * v.x + v.y * v.y + v.z * v.z + v.w * v.w;
#pragma unroll
  for (int m = 1; m < 64; m <<= 1) {
    s += __shfl_xor(s, m);
    s2 += __shfl_xor(s2, m);
  }
  __shared__ float ps[4], ps2[4];
  int wv_ = tid >> 6, lane = tid & 63;
  if (lane == 0) { ps[wv_] = s; ps2[wv_] = s2; }
  __syncthreads();
  float ts = ps[0] + ps[1] + ps[2] + ps[3];
  float ts2 = ps2[0] + ps2[1] + ps2[2] + ps2[3];
  float mu = ts * (1.0f / DD);
  float var = ts2 * (1.0f / DD) - mu * mu;
  float rs = rsqrtf(var + 1e-5f);
  float4 wv = *(const float4*)&w[tid * 4];
  float4 bv = *(const float4*)&b[tid * 4];
  __hip_bfloat16 o[4];
  o[0] = __float2bfloat16((v.x - mu) * rs * wv.x + bv.x);
  o[1] = __float2bfloat16((v.y - mu) * rs * wv.y + bv.y);
  o[2] = __float2bfloat16((v.z - mu) * rs * wv.z + bv.z);
  o[3] = __float2bfloat16((v.w - mu) * rs * wv.w + bv.w);
  *(uint2*)&out[(size_t)row * DD + tid * 4] = *(const uint2*)o;
}

// ===================== 256x128 GEMM, triple-buffered gload_lds (QKV) =====================
template <int EPI>
__global__ __launch_bounds__(512, 4) void gemm256x128(const __hip_bfloat16* __restrict__ A,
                                                      const __hip_bfloat16* __restrict__ Bt,
                                                      const float* __restrict__ bias,
                                                      const float* __restrict__ resid,
                                                      void* __restrict__ Cout,
                                                      int M, int N, int K) {
  __shared__ __hip_bfloat16 Ab[3][256][32];  // 3 x 16 KB
  __shared__ __hip_bfloat16 Bb[3][128][32];  // 3 x 8 KB
  const int tid = threadIdx.x, lane = tid & 63, w = tid >> 6;
  const int wm = w >> 1, wn = w & 1;  // 4M x 2N waves

  int nbx = gridDim.x, nwg = nbx * gridDim.y;
  int orig = blockIdx.y * nbx + blockIdx.x;
  int cpx = nwg >> 3;
  int wgid = (orig & 7) * cpx + (orig >> 3);  // grids %8==0
  int bm0 = (wgid / nbx) * 256, bn0 = (wgid % nbx) * 128;

  const int fr = lane & 15, kq = lane >> 4;
  const int sg = ((lane & 3) ^ ((lane >> 3) & 3)) * 8;  // inverse-swizzled src col
  const int srw = lane >> 2;

  auto stageA = [&](int c, int g, int k0) {
    int u = w * 2 + g;
    const __hip_bfloat16* src = A + (size_t)(bm0 + u * 16 + srw) * K + k0 + sg;
    GLOAD16(src, (char*)Ab + c * 16384 + u * 1024);
  };
  auto stageB = [&](int c, int k0) {
    const __hip_bfloat16* src = Bt + (size_t)(bn0 + w * 16 + srw) * K + k0 + sg;
    GLOAD16(src, (char*)Bb + c * 8192 + w * 1024);
  };
  const int swz = ((kq ^ ((fr >> 1) & 3)) << 4);
  auto ldA = [&](int c, int r) -> bf16x8 {
    return *(const bf16x8*)((const char*)Ab + c * 16384 + r * 64 + swz);
  };
  auto ldB = [&](int c, int r) -> bf16x8 {
    return *(const bf16x8*)((const char*)Bb + c * 8192 + r * 64 + swz);
  };

  f32x4 acc[4][4] = {};
  bf16x8 a[4], b[4];

  const int nt = K >> 5;
#pragma unroll
  for (int tt = 0; tt < 2; ++tt) {
    stageA(tt, 0, tt * 32); stageA(tt, 1, tt * 32); stageB(tt, tt * 32);
  }
  asm volatile("s_waitcnt vmcnt(3)" ::: "memory");
  BARRIER;

  int cur = 0, nxt = 2;
  for (int t = 0; t < nt; ++t) {
#pragma unroll
    for (int mf = 0; mf < 4; ++mf) a[mf] = ldA(cur, wm * 64 + mf * 16 + fr);
#pragma unroll
    for (int nf = 0; nf < 4; ++nf) b[nf] = ldB(cur, wn * 64 + nf * 16 + fr);
    if (t + 2 < nt) {
      stageA(nxt, 0, (t + 2) * 32); stageA(nxt, 1, (t + 2) * 32); stageB(nxt, (t + 2) * 32);
    }
    __builtin_amdgcn_s_setprio(1);
#pragma unroll
    for (int mf = 0; mf < 4; ++mf)
#pragma unroll
      for (int nf = 0; nf < 4; ++nf)
        acc[mf][nf] = __builtin_amdgcn_mfma_f32_16x16x32_bf16(a[mf], b[nf], acc[mf][nf], 0, 0, 0);
    __builtin_amdgcn_s_setprio(0);
    if (t <= nt - 3)      { asm volatile("s_waitcnt vmcnt(3)" ::: "memory"); }
    else if (t == nt - 2) { asm volatile("s_waitcnt vmcnt(0)" ::: "memory"); }
    BARRIER;
    cur = (cur == 2) ? 0 : cur + 1;
    nxt = (nxt == 2) ? 0 : nxt + 1;
  }

#pragma unroll
  for (int nf = 0; nf < 4; ++nf) {
    int col = bn0 + wn * 64 + nf * 16 + fr;
    float bsv = bias[col];
#pragma unroll
    for (int mf = 0; mf < 4; ++mf) {
      int rowb = bm0 + wm * 64 + mf * 16 + kq * 4;
#pragma unroll
      for (int j = 0; j < 4; ++j) {
        int row = rowb + j;
        float v = acc[mf][nf][j] + bsv;
        if (EPI == 1) v = 0.5f * v * (1.0f + erff(v * 0.7071067811865476f));
        if (EPI == 2) {
          ((float*)Cout)[(size_t)row * N + col] = v + resid[(size_t)row * N + col];
        } else {
          ((__hip_bfloat16*)Cout)[(size_t)row * N + col] = __float2bfloat16(v);
        }
      }
    }
  }
}

// ===================== 128x128 GEMM, BK=64, double-buffered (FC1 — 55.0us measured) =====================
template <int EPI>
__global__ __launch_bounds__(512, 4) void gemm128bk64(const __hip_bfloat16* __restrict__ A,
                                                      const __hip_bfloat16* __restrict__ Bt,
                                                      const float* __restrict__ bias,
                                                      const float* __restrict__ resid,
                                                      void* __restrict__ Cout,
                                                      int M, int N, int K) {
  __shared__ __hip_bfloat16 Ab[2][128][64];  // 2 x 16 KB
  __shared__ __hip_bfloat16 Bb[2][128][64];  // 2 x 16 KB
  const int tid = threadIdx.x, lane = tid & 63, w = tid >> 6;
  const int wm = w >> 2, wn = w & 3;  // 2M x 4N waves

  int nbx = gridDim.x, nwg = nbx * gridDim.y;
  int orig = blockIdx.y * nbx + blockIdx.x;
  int cpx = nwg >> 3;
  int wgid = (orig & 7) * cpx + (orig >> 3);  // grids %8==0
  int bm0 = (wgid / nbx) * 128, bn0 = (wgid % nbx) * 128;

  const int fr = lane & 15, kq = lane >> 4;
  const int srw = lane >> 3;                      // row within 8-row unit
  const int sg = ((lane & 7) ^ (lane >> 3)) * 8;  // inverse-swizzled src col (elems)

  auto stageA = [&](int c, int j, int k0) {
    int u = 2 * w + j;  // 0..15
    const __hip_bfloat16* src = A + (size_t)(bm0 + u * 8 + srw) * K + k0 + sg;
    GLOAD16(src, (char*)Ab + c * 16384 + u * 1024);
  };
  auto stageB = [&](int c, int j, int k0) {
    int u = 2 * w + j;
    const __hip_bfloat16* src = Bt + (size_t)(bn0 + u * 8 + srw) * K + k0 + sg;
    GLOAD16(src, (char*)Bb + c * 16384 + u * 1024);
  };
  auto ldA = [&](int c, int r, int ks) -> bf16x8 {
    int byte = r * 128 + ((ks * 64 + kq * 16) ^ ((r & 7) << 4));
    return *(const bf16x8*)((const char*)Ab + c * 16384 + byte);
  };
  auto ldB = [&](int c, int r, int ks) -> bf16x8 {
    int byte = r * 128 + ((ks * 64 + kq * 16) ^ ((r & 7) << 4));
    return *(const bf16x8*)((const char*)Bb + c * 16384 + byte);
  };

  f32x4 acc[4][2] = {};
  bf16x8 a[4][2], b[2][2];

  const int nt = K >> 6;
  stageA(0, 0, 0);  stageA(0, 1, 0);  stageB(0, 0, 0);  stageB(0, 1, 0);
  stageA(1, 0, 64); stageA(1, 1, 64); stageB(1, 0, 64); stageB(1, 1, 64);
  asm volatile("s_waitcnt vmcnt(4)" ::: "memory");
  BARRIER;

  for (int t = 0; t < nt; ++t) {
    const int cur = t & 1;
#pragma unroll
    for (int mf = 0; mf < 4; ++mf)
#pragma unroll
      for (int ks = 0; ks < 2; ++ks)
        a[mf][ks] = ldA(cur, wm * 64 + mf * 16 + fr, ks);
#pragma unroll
    for (int nf = 0; nf < 2; ++nf)
#pragma unroll
      for (int ks = 0; ks < 2; ++ks)
        b[nf][ks] = ldB(cur, wn * 32 + nf * 16 + fr, ks);
    __builtin_amdgcn_s_setprio(1);
#pragma unroll
    for (int mf = 0; mf < 4; ++mf)
#pragma unroll
      for (int nf = 0; nf < 2; ++nf)
#pragma unroll
        for (int ks = 0; ks < 2; ++ks)
          acc[mf][nf] = __builtin_amdgcn_mfma_f32_16x16x32_bf16(
              a[mf][ks], b[nf][ks], acc[mf][nf], 0, 0, 0);
    __builtin_amdgcn_s_setprio(0);
    BARRIER;
    if (t + 2 < nt) {
      int kn = (t + 2) * 64;
      stageA(cur, 0, kn); stageA(cur, 1, kn); stageB(cur, 0, kn); stageB(cur, 1, kn);
      asm volatile("s_waitcnt vmcnt(4)" ::: "memory");
    } else if (t + 1 < nt) {
      asm volatile("s_waitcnt vmcnt(0)" ::: "memory");
    }
    BARRIER;
  }

#pragma unroll
  for (int nf = 0; nf < 2; ++nf) {
    int col = bn0 + wn * 32 + nf * 16 + fr;
    float bsv = bias[col];
#pragma unroll
    for (int mf = 0; mf < 4; ++mf) {
      int rowb = bm0 + wm * 64 + mf * 16 + kq * 4;
#pragma unroll
      for (int j = 0; j < 4; ++j) {
        int row = rowb + j;
        float v = acc[mf][nf][j] + bsv;
        if (EPI == 1) v = 0.5f * v * (1.0f + erff(v * 0.7071067811865476f));
        if (EPI == 2) {
          ((float*)Cout)[(size_t)row * N + col] = v + resid[(size_t)row * N + col];
        } else {
          ((__hip_bfloat16*)Cout)[(size_t)row * N + col] = __float2bfloat16(v);
        }
      }
    }
  }
}

// ===================== 128x64 GEMM, 8 waves, BK=64, triple-buffered (proj/FC2) =====================
template <int EPI>
__global__ __launch_bounds__(512, 4) void gemm128x64w8(const __hip_bfloat16* __restrict__ A,
                                                       const __hip_bfloat16* __restrict__ Bt,
                                                       const float* __restrict__ bias,
                                                       const float* __restrict__ resid,
                                                       void* __restrict__ Cout,
                                                       int M, int N, int K) {
  __shared__ __hip_bfloat16 Ab[3][128][64];  // 3 x 16 KB
  __shared__ __hip_bfloat16 Bb[3][64][64];   // 3 x 8 KB
  const int tid = threadIdx.x, lane = tid & 63, w = tid >> 6;
  const int wm = w >> 1, wn = w & 1;

  int nbx = gridDim.x, nwg = nbx * gridDim.y;
  int orig = blockIdx.y * nbx + blockIdx.x;
  int cpx = nwg >> 3;
  int wgid = (orig & 7) * cpx + (orig >> 3);
  int bm0 = (wgid / nbx) * 128, bn0 = (wgid % nbx) * 64;

  const int fr = lane & 15, kq = lane >> 4;
  const int srw = lane >> 3;
  const int sg = ((lane & 7) ^ (lane >> 3)) * 8;

  auto stageA = [&](int c, int j, int k0) {
    int u = 2 * w + j;
    const __hip_bfloat16* src = A + (size_t)(bm0 + u * 8 + srw) * K + k0 + sg;
    GLOAD16(src, (char*)Ab + c * 16384 + u * 1024);
  };
  auto stageB = [&](int c, int k0) {
    const __hip_bfloat16* src = Bt + (size_t)(bn0 + w * 8 + srw) * K + k0 + sg;
    GLOAD16(src, (char*)Bb + c * 8192 + w * 1024);
  };
  auto ldA = [&](int c, int r, int ks) -> bf16x8 {
    int byte = r * 128 + ((ks * 64 + kq * 16) ^ ((r & 7) << 4));
    return *(const bf16x8*)((const char*)Ab + c * 16384 + byte);
  };
  auto ldB = [&](int c, int r, int ks) -> bf16x8 {
    int byte = r * 128 + ((ks * 64 + kq * 16) ^ ((r & 7) << 4));
    return *(const bf16x8*)((const char*)Bb + c * 8192 + byte);
  };

  f32x4 acc[2][2] = {};
  bf16x8 a[2][2], b[2][2];

  const int nt = K >> 6;
#pragma unroll
  for (int tt = 0; tt < 2; ++tt) {
    stageA(tt, 0, tt * 64); stageA(tt, 1, tt * 64); stageB(tt, tt * 64);
  }
  asm volatile("s_waitcnt vmcnt(3)" ::: "memory");
  BARRIER;

  int cur = 0, nxt = 2;
  for (int t = 0; t < nt; ++t) {
#pragma unroll
    for (int mf = 0; mf < 2; ++mf)
#pragma unroll
      for (int ks = 0; ks < 2; ++ks)
        a[mf][ks] = ldA(cur, wm * 32 + mf * 16 + fr, ks);
#pragma unroll
    for (int nf = 0; nf < 2; ++nf)
#pragma unroll
      for (int ks = 0; ks < 2; ++ks)
        b[nf][ks] = ldB(cur, wn * 32 + nf * 16 + fr, ks);
    if (t + 2 < nt) {
      stageA(nxt, 0, (t + 2) * 64); stageA(nxt, 1, (t + 2) * 64); stageB(nxt, (t + 2) * 64);
    }
    __builtin_amdgcn_s_setprio(1);
#pragma unroll
    for (int mf = 0; mf < 2; ++mf)
#pragma unroll
      for (int nf = 0; nf < 2; ++nf)
#pragma unroll
        for (int ks = 0; ks < 2; ++ks)
          acc[mf][nf] = __builtin_amdgcn_mfma_f32_16x16x32_bf16(
              a[mf][ks], b[nf][ks], acc[mf][nf], 0, 0, 0);
    __builtin_amdgcn_s_setprio(0);
    if (t <= nt - 3)      { asm volatile("s_waitcnt vmcnt(3)" ::: "memory"); }
    else if (t == nt - 2) { asm volatile("s_waitcnt vmcnt(0)" ::: "memory"); }
    BARRIER;
    cur = (cur == 2) ? 0 : cur + 1;
    nxt = (nxt == 2) ? 0 : nxt + 1;
  }

#pragma unroll
  for (int nf = 0; nf < 2; ++nf) {
    int col = bn0 + wn * 32 + nf * 16 + fr;
    float bsv = bias[col];
#pragma unroll
    for (int mf = 0; mf < 2; ++mf) {
      int rowb = bm0 + wm * 32 + mf * 16 + kq * 4;
#pragma unroll
      for (int j = 0; j < 4; ++j) {
        int row = rowb + j;
        float v = acc[mf][nf][j] + bsv;
        if (EPI == 1) v = 0.5f * v * (1.0f + erff(v * 0.7071067811865476f));
        if (EPI == 2) {
          ((float*)Cout)[(size_t)row * N + col] = v + resid[(size_t)row * N + col];
        } else {
          ((__hip_bfloat16*)Cout)[(size_t)row * N + col] = __float2bfloat16(v);
        }
      }
    }
  }
}

// ---------------- MFMA flash attention, defer-max (unchanged) ----------------
__global__ __launch_bounds__(256) void attn_mfma(const __hip_bfloat16* __restrict__ qkv,
                                                 const __hip_bfloat16* __restrict__ Erb,
                                                 __hip_bfloat16* __restrict__ Y) {
  __shared__ __hip_bfloat16 k_s[64][72];
  __shared__ __hip_bfloat16 er_s[64][72];
  __shared__ __hip_bfloat16 p_s[4][16][72];
  __shared__ __hip_bfloat16 g_s[4][16][132];
  __shared__ __hip_bfloat16 vt_s[64 * 64];

  int bid = blockIdx.x;
  int qi = 15 - (bid >> 6);
  int head = bid & 63;
  int h = head & 15, b = head >> 4;
  int l0 = qi * 64;
  int tid = threadIdx.x, lane = tid & 63, w = tid >> 6;
  const int fr = lane & 15, kq = lane >> 4;

  const __hip_bfloat16* base = qkv + (size_t)b * (LL * 3072) + h * 64;

  bf16x8 qf[2];
  {
    const __hip_bfloat16* q0 = base + (size_t)(l0 + 16 * w + fr) * 3072 + kq * 8;
    qf[0] = *(const bf16x8*)q0;
    qf[1] = *(const bf16x8*)(q0 + 32);
  }

  const int ksr = tid >> 2, ksd = (tid & 3) * 16;
  const __hip_bfloat16* ksrc = base + 1024 + (size_t)ksr * 3072 + ksd;
  const int vc = (tid >> 3) * 2, vd0 = (tid & 7) * 8;
  const __hip_bfloat16* vsrc = base + 2048 + (size_t)vc * 3072 + vd0;
  const int err = tid >> 2, erc = (tid & 3) * 16;

  uint4 kst0, kst1, vst0, vst1;
  uint4 ers0, ers1;
  uint4 ec10, ec11;

  {
    kst0 = *(const uint4*)ksrc; kst1 = *(const uint4*)(ksrc + 8);
    vst0 = *(const uint4*)vsrc; vst1 = *(const uint4*)(vsrc + 3072);
    int m0 = min(max(960 - l0 + err, 0), 1023);
    const __hip_bfloat16* ep0 = Erb + (size_t)m0 * 64 + erc;
    ers0 = *(const uint4*)ep0; ers1 = *(const uint4*)(ep0 + 8);
    if (qi > 0) {
      int m1 = min(max(960 - l0 + 64 + err, 0), 1023);
      const __hip_bfloat16* ep1 = Erb + (size_t)m1 * 64 + erc;
      ec10 = *(const uint4*)ep1; ec11 = *(const uint4*)(ep1 + 8);
    }
  }

  f32x4 oacc[4] = {};
  float m_run[4], s_run[4];
#pragma unroll
  for (int j = 0; j < 4; ++j) { m_run[j] = -1e30f; s_run[j] = 0.f; }

  auto gchunk = [&](int hf) {
#pragma unroll
    for (int g = 0; g < 4; ++g) {
      int cc = 16 * g + fr, kc = kq * 8;
      bf16x8 e0 = *(const bf16x8*)&er_s[cc][kc];
      bf16x8 e1 = *(const bf16x8*)&er_s[cc][kc + 32];
      f32x4 gacc = {};
      gacc = __builtin_amdgcn_mfma_f32_16x16x32_bf16(qf[0], e0, gacc, 0, 0, 0);
      gacc = __builtin_amdgcn_mfma_f32_16x16x32_bf16(qf[1], e1, gacc, 0, 0, 0);
#pragma unroll
      for (int j = 0; j < 4; ++j)
        g_s[w][kq * 4 + j][hf * 64 + 16 * g + fr] = __float2bfloat16(gacc[j]);
    }
  };

  for (int t = 0; t <= qi; ++t) {
    __syncthreads();
    *(uint4*)&k_s[ksr][ksd] = kst0;
    *(uint4*)&k_s[ksr][ksd + 8] = kst1;
    {
      const uint16_t* h0 = (const uint16_t*)&vst0;
      const uint16_t* h1 = (const uint16_t*)&vst1;
#pragma unroll
      for (int j = 0; j < 8; ++j) {
        int d = vd0 + j;
        uint32_t pk = (uint32_t)h0[j] | ((uint32_t)h1[j] << 16);
        uint32_t byte = ((uint32_t)d << 7) + 2u * (uint32_t)vc;
        byte ^= (uint32_t)(((d & 7) ^ (d >> 3)) << 4);
        *(uint32_t*)((char*)vt_s + byte) = pk;
      }
    }
    if (t == 0 || t < qi) {
      *(uint4*)&er_s[err][erc]     = ers0;
      *(uint4*)&er_s[err][erc + 8] = ers1;
    }
    __syncthreads();
    if (t < qi) {
      int c0n = (t + 1) * 64;
      const __hip_bfloat16* kp = ksrc + (size_t)c0n * 3072;
      kst0 = *(const uint4*)kp; kst1 = *(const uint4*)(kp + 8);
      const __hip_bfloat16* vp = vsrc + (size_t)c0n * 3072;
      vst0 = *(const uint4*)vp; vst1 = *(const uint4*)(vp + 3072);
      if (t + 1 < qi) {
        int m = min(960 - l0 + (t + 2) * 64 + err, 1023);
        const __hip_bfloat16* ep = Erb + (size_t)m * 64 + erc;
        ers0 = *(const uint4*)ep; ers1 = *(const uint4*)(ep + 8);
      }
    }
    SCHEDB;

    f32x4 sacc[4] = {};
#pragma unroll
    for (int f = 0; f < 4; ++f) {
      int cc = 16 * f + fr, kc = kq * 8;
      bf16x8 k0 = *(const bf16x8*)&k_s[cc][kc];
      bf16x8 k1 = *(const bf16x8*)&k_s[cc][kc + 32];
      sacc[f] = __builtin_amdgcn_mfma_f32_16x16x32_bf16(qf[0], k0, sacc[f], 0, 0, 0);
      sacc[f] = __builtin_amdgcn_mfma_f32_16x16x32_bf16(qf[1], k1, sacc[f], 0, 0, 0);
    }
    if (t == 0) {
      gchunk(0);
      if (qi > 0) {
        __syncthreads();
        *(uint4*)&er_s[err][erc]     = ec10;
        *(uint4*)&er_s[err][erc + 8] = ec11;
        __syncthreads();
        gchunk(1);
      }
    } else if (t < qi) {
      gchunk((t + 1) & 1);
    }

    float sv[4][4];
#pragma unroll
    for (int f = 0; f < 4; ++f) {
#pragma unroll
      for (int j = 0; j < 4; ++j) {
        int r = kq * 4 + j;
        int c = 16 * f + fr;
        int jj = c - (16 * w + r) + 63;
        float g = __bfloat162float(g_s[w][r][(t * 64 + jj) & 127]);
        float val = (sacc[f][j] + g) * 0.125f;
        if (t == qi && c > 16 * w + r) val = -1e30f;
        sv[f][j] = val;
      }
    }
    float tm[4];
#pragma unroll
    for (int j = 0; j < 4; ++j) {
      float m_ = fmaxf(fmaxf(sv[0][j], sv[1][j]), fmaxf(sv[2][j], sv[3][j]));
      m_ = fmaxf(m_, __shfl_xor(m_, 1));
      m_ = fmaxf(m_, __shfl_xor(m_, 2));
      m_ = fmaxf(m_, __shfl_xor(m_, 4));
      m_ = fmaxf(m_, __shfl_xor(m_, 8));
      tm[j] = m_;
    }
    bool need = (tm[0] > m_run[0] + 8.f) || (tm[1] > m_run[1] + 8.f) ||
                (tm[2] > m_run[2] + 8.f) || (tm[3] > m_run[3] + 8.f);
    float alpha[4];
    if (need) {
#pragma unroll
      for (int j = 0; j < 4; ++j) {
        float nm = fmaxf(m_run[j], tm[j]);
        alpha[j] = __expf(m_run[j] - nm);
        m_run[j] = nm;
      }
    }
#pragma unroll
    for (int f = 0; f < 4; ++f)
#pragma unroll
      for (int j = 0; j < 4; ++j)
        sv[f][j] = __expf(sv[f][j] - m_run[j]);
#pragma unroll
    for (int j = 0; j < 4; ++j) {
      float ps = sv[0][j] + sv[1][j] + sv[2][j] + sv[3][j];
      ps += __shfl_xor(ps, 1); ps += __shfl_xor(ps, 2);
      ps += __shfl_xor(ps, 4); ps += __shfl_xor(ps, 8);
      s_run[j] = (need ? s_run[j] * alpha[j] : s_run[j]) + ps;
    }
    if (need) {
#pragma unroll
      for (int f = 0; f < 4; ++f)
#pragma unroll
        for (int j = 0; j < 4; ++j)
          oacc[f][j] *= alpha[j];
    }
#pragma unroll
    for (int f = 0; f < 4; ++f)
#pragma unroll
      for (int j = 0; j < 4; ++j)
        p_s[w][kq * 4 + j][16 * f + fr] = __float2bfloat16(sv[f][j]);
#pragma unroll
    for (int kk = 0; kk < 2; ++kk) {
      bf16x8 pf = *(const bf16x8*)&p_s[w][fr][kq * 8 + 32 * kk];
#pragma unroll
      for (int f = 0; f < 4; ++f) {
        int d = 16 * f + fr;
        int cc = kq * 8 + 32 * kk;
        uint32_t byte = ((uint32_t)d << 7) + 2u * (uint32_t)cc;
        byte ^= (uint32_t)(((d & 7) ^ (d >> 3)) << 4);
        bf16x8 vf = *(const bf16x8*)((char*)vt_s + byte);
        oacc[f] = __builtin_amdgcn_mfma_f32_16x16x32_bf16(pf, vf, oacc[f], 0, 0, 0);
      }
    }
  }

#pragma unroll
  for (int f = 0; f < 4; ++f)
#pragma unroll
    for (int j = 0; j < 4; ++j) {
      int r = 16 * w + kq * 4 + j;
      int d = 16 * f + fr;
      float o = oacc[f][j] / s_run[j];
      Y[(size_t)(b * LL + l0 + r) * DD + h * 64 + d] = __float2bfloat16(o);
    }
}

// ---------------- launch ----------------
extern "C" void kernel_launch(void* const* d_in, const int* in_sizes, int n_in,
                              void* d_out, int out_size, void* d_ws, size_t ws_size,
                              hipStream_t stream) {
  (void)in_sizes; (void)n_in; (void)out_size; (void)ws_size;
  const float* x     = (const float*)d_in[0];
  const float* ln1w  = (const float*)d_in[1];
  const float* ln1b  = (const float*)d_in[2];
  const float* Wqkv  = (const float*)d_in[3];
  const float* bqkv  = (const float*)d_in[4];
  const float* Wproj = (const float*)d_in[5];
  const float* bproj = (const float*)d_in[6];
  const float* Er    = (const float*)d_in[7];
  const float* ln2w  = (const float*)d_in[8];
  const float* ln2b  = (const float*)d_in[9];
  const float* Wfc   = (const float*)d_in[10];
  const float* bfc   = (const float*)d_in[11];
  const float* Wfc2  = (const float*)d_in[12];
  const float* bfc2  = (const float*)d_in[13];
  float* out = (float*)d_out;

  char* ws = (char*)d_ws;
  const size_t MB = 1ull << 20;
  __hip_bfloat16* h1    = (__hip_bfloat16*)(ws + 0);        // 8 MB
  __hip_bfloat16* qkvb  = (__hip_bfloat16*)(ws + 8 * MB);   // 24 MB
  __hip_bfloat16* mbuf  = (__hip_bfloat16*)(ws + 0);        // 32 MB (aliases h1+qkvb)
  __hip_bfloat16* yb    = (__hip_bfloat16*)(ws + 32 * MB);  // 8 MB
  __hip_bfloat16* h2    = (__hip_bfloat16*)(ws + 32 * MB);  // 8 MB (aliases yb)
  float*          x2    = (float*)(ws + 40 * MB);           // 16 MB
  __hip_bfloat16* Wqkvt = (__hip_bfloat16*)(ws + 56 * MB);  // 6 MB
  __hip_bfloat16* Erb   = (__hip_bfloat16*)(ws + 62 * MB);  // 128 KB
  __hip_bfloat16* Wprojt= (__hip_bfloat16*)(ws + 63 * MB);  // 2 MB
  __hip_bfloat16* Wfct  = (__hip_bfloat16*)(ws + 66 * MB);  // 8 MB
  __hip_bfloat16* Wfc2t = (__hip_bfloat16*)(ws + 75 * MB);  // 8 MB

  dim3 blk(256);

  prep_weights<<<dim3(16448), blk, 0, stream>>>(Wqkv, Wproj, Wfc, Wfc2, Er,
                                                x, ln1w, ln1b,
                                                Wqkvt, Wprojt, Wfct, Wfc2t, Erb, h1);

  gemm256x128<0><<<dim3(3072 / 128, 4096 / 256), dim3(512), 0, stream>>>(
      h1, Wqkvt, bqkv, nullptr, qkvb, 4096, 3072, 1024);

  attn_mfma<<<dim3(1024), blk, 0, stream>>>(qkvb, Erb, yb);

  gemm128x64w8<2><<<dim3(1024 / 64, 4096 / 128), dim3(512), 0, stream>>>(
      yb, Wprojt, bproj, x, x2, 4096, 1024, 1024);

  ln_kernel<<<4096, blk, 0, stream>>>(x2, ln2w, ln2b, h2);

  gemm128bk64<1><<<dim3(4096 / 128, 4096 / 128), dim3(512), 0, stream>>>(
      h2, Wfct, bfc, nullptr, mbuf, 4096, 4096, 1024);

  gemm128x64w8<2><<<dim3(1024 / 64, 4096 / 128), dim3(512), 0, stream>>>(
      mbuf, Wfc2t, bfc2, x2, out, 4096, 1024, 4096);
}

// Round 24
// 216.799 us; speedup vs baseline: 1.0237x; 1.0122x over previous
//
#include <hip/hip_runtime.h>
#include <hip/hip_bf16.h>
#include <math.h>

typedef __attribute__((ext_vector_type(8))) __bf16 bf16x8;
typedef __attribute__((ext_vector_type(4))) float f32x4;

#define LL 1024
#define DD 1024
#define HH 16

#define GLOAD16(g, l)                                              \
  __builtin_amdgcn_global_load_lds(                                \
      (const __attribute__((address_space(1))) void*)(g),          \
      (__attribute__((address_space(3))) void*)(l), 16, 0, 0)

#define FENCE asm volatile("" ::: "memory")
#define SCHEDB __builtin_amdgcn_sched_barrier(0)
#define BARRIER do { FENCE; __builtin_amdgcn_s_barrier(); FENCE; } while (0)

// ---------------- merged prep: 4 transposes + Er cvt + LN1 in ONE dispatch ----------------
__global__ __launch_bounds__(256) void prep_weights(const float* __restrict__ Wqkv,
                                                    const float* __restrict__ Wproj,
                                                    const float* __restrict__ Wfc,
                                                    const float* __restrict__ Wfc2,
                                                    const float* __restrict__ Er,
                                                    const float* __restrict__ X,
                                                    const float* __restrict__ ln1w,
                                                    const float* __restrict__ ln1b,
                                                    __hip_bfloat16* __restrict__ Wqkvt,
                                                    __hip_bfloat16* __restrict__ Wprojt,
                                                    __hip_bfloat16* __restrict__ Wfct,
                                                    __hip_bfloat16* __restrict__ Wfc2t,
                                                    __hip_bfloat16* __restrict__ Erb,
                                                    __hip_bfloat16* __restrict__ h1) {
  int bid = blockIdx.x;
  int tx = threadIdx.x;
  if (bid >= 12352) {  // ---- LN1 row ----
    int row = bid - 12352;
    const float* xr = X + (size_t)row * DD;
    float4 v = *(const float4*)&xr[tx * 4];
    float s = v.x + v.y + v.z + v.w;
    float s2 = v.x * v.x + v.y * v.y + v.z * v.z + v.w * v.w;
#pragma unroll
    for (int m = 1; m < 64; m <<= 1) {
      s += __shfl_xor(s, m);
      s2 += __shfl_xor(s2, m);
    }
    __shared__ float ps[4], ps2[4];
    int wv_ = tx >> 6, lane = tx & 63;
    if (lane == 0) { ps[wv_] = s; ps2[wv_] = s2; }
    __syncthreads();
    float ts = ps[0] + ps[1] + ps[2] + ps[3];
    float ts2 = ps2[0] + ps2[1] + ps2[2] + ps2[3];
    float mu = ts * (1.0f / DD);
    float var = ts2 * (1.0f / DD) - mu * mu;
    float rs = rsqrtf(var + 1e-5f);
    float4 wv = *(const float4*)&ln1w[tx * 4];
    float4 bv = *(const float4*)&ln1b[tx * 4];
    __hip_bfloat16 o[4];
    o[0] = __float2bfloat16((v.x - mu) * rs * wv.x + bv.x);
    o[1] = __float2bfloat16((v.y - mu) * rs * wv.y + bv.y);
    o[2] = __float2bfloat16((v.z - mu) * rs * wv.z + bv.z);
    o[3] = __float2bfloat16((v.w - mu) * rs * wv.w + bv.w);
    *(uint2*)&h1[(size_t)row * DD + tx * 4] = *(const uint2*)o;
    return;
  }
  if (bid >= 12288) {  // ---- cvt_er ----
    int i = (bid - 12288) * 256 + tx;
    float4 v = *(const float4*)&Er[(size_t)i * 4];
    __hip_bfloat16 o[4];
    o[0] = __float2bfloat16(v.x); o[1] = __float2bfloat16(v.y);
    o[2] = __float2bfloat16(v.z); o[3] = __float2bfloat16(v.w);
    *(uint2*)&Erb[(size_t)i * 4] = *(const uint2*)o;
    return;
  }
  const float* W; __hip_bfloat16* Wt; int R, C, local;
  if (bid < 3072)      { W = Wqkv;  Wt = Wqkvt;  R = 1024; C = 3072; local = bid; }
  else if (bid < 4096) { W = Wproj; Wt = Wprojt; R = 1024; C = 1024; local = bid - 3072; }
  else if (bid < 8192) { W = Wfc;   Wt = Wfct;   R = 1024; C = 4096; local = bid - 4096; }
  else                 { W = Wfc2;  Wt = Wfc2t;  R = 4096; C = 1024; local = bid - 8192; }
  int nbx = C / 32;
  int r0 = (local / nbx) * 32, c0 = (local % nbx) * 32;
  __shared__ float tile[32][33];
  int r = tx >> 3, c4 = (tx & 7) * 4;
  float4 v = *(const float4*)&W[(size_t)(r0 + r) * C + c0 + c4];
  tile[r][c4 + 0] = v.x; tile[r][c4 + 1] = v.y;
  tile[r][c4 + 2] = v.z; tile[r][c4 + 3] = v.w;
  __syncthreads();
  int c = tx >> 3, r4 = (tx & 7) * 4;
  __hip_bfloat16 o[4];
#pragma unroll
  for (int j = 0; j < 4; ++j) o[j] = __float2bfloat16(tile[r4 + j][c]);
  *(uint2*)&Wt[(size_t)(c0 + c) * R + r0 + r4] = *(const uint2*)o;
}

// ---------------- layernorm (fp32 in -> bf16 out) ----------------
__global__ __launch_bounds__(256) void ln_kernel(const float* __restrict__ X,
                                                 const float* __restrict__ w,
                                                 const float* __restrict__ b,
                                                 __hip_bfloat16* __restrict__ out) {
  int row = blockIdx.x;
  int tid = threadIdx.x;
  const float* xr = X + (size_t)row * DD;
  float4 v = *(const float4*)&xr[tid * 4];
  float s = v.x + v.y + v.z + v.w;
  float s2 = v.x * v.x + v.y * v.y + v.z * v.z + v.w * v.w;
#pragma unroll
  for (int m = 1; m < 64; m <<= 1) {
    s += __shfl_xor(s, m);
    s2 += __shfl_xor(s2, m);
  }
  __shared__ float ps[4], ps2[4];
  int wv_ = tid >> 6, lane = tid & 63;
  if (lane == 0) { ps[wv_] = s; ps2[wv_] = s2; }
  __syncthreads();
  float ts = ps[0] + ps[1] + ps[2] + ps[3];
  float ts2 = ps2[0] + ps2[1] + ps2[2] + ps2[3];
  float mu = ts * (1.0f / DD);
  float var = ts2 * (1.0f / DD) - mu * mu;
  float rs = rsqrtf(var + 1e-5f);
  float4 wv = *(const float4*)&w[tid * 4];
  float4 bv = *(const float4*)&b[tid * 4];
  __hip_bfloat16 o[4];
  o[0] = __float2bfloat16((v.x - mu) * rs * wv.x + bv.x);
  o[1] = __float2bfloat16((v.y - mu) * rs * wv.y + bv.y);
  o[2] = __float2bfloat16((v.z - mu) * rs * wv.z + bv.z);
  o[3] = __float2bfloat16((v.w - mu) * rs * wv.w + bv.w);
  *(uint2*)&out[(size_t)row * DD + tid * 4] = *(const uint2*)o;
}

// ===================== 256x128 GEMM, triple-buffered gload_lds (QKV) =====================
template <int EPI>
__global__ __launch_bounds__(512, 4) void gemm256x128(const __hip_bfloat16* __restrict__ A,
                                                      const __hip_bfloat16* __restrict__ Bt,
                                                      const float* __restrict__ bias,
                                                      const float* __restrict__ resid,
                                                      void* __restrict__ Cout,
                                                      int M, int N, int K) {
  __shared__ __hip_bfloat16 Ab[3][256][32];  // 3 x 16 KB
  __shared__ __hip_bfloat16 Bb[3][128][32];  // 3 x 8 KB
  const int tid = threadIdx.x, lane = tid & 63, w = tid >> 6;
  const int wm = w >> 1, wn = w & 1;  // 4M x 2N waves

  int nbx = gridDim.x, nwg = nbx * gridDim.y;
  int orig = blockIdx.y * nbx + blockIdx.x;
  int cpx = nwg >> 3;
  int wgid = (orig & 7) * cpx + (orig >> 3);  // grids %8==0
  int bm0 = (wgid / nbx) * 256, bn0 = (wgid % nbx) * 128;

  const int fr = lane & 15, kq = lane >> 4;
  const int sg = ((lane & 3) ^ ((lane >> 3) & 3)) * 8;  // inverse-swizzled src col
  const int srw = lane >> 2;

  auto stageA = [&](int c, int g, int k0) {
    int u = w * 2 + g;
    const __hip_bfloat16* src = A + (size_t)(bm0 + u * 16 + srw) * K + k0 + sg;
    GLOAD16(src, (char*)Ab + c * 16384 + u * 1024);
  };
  auto stageB = [&](int c, int k0) {
    const __hip_bfloat16* src = Bt + (size_t)(bn0 + w * 16 + srw) * K + k0 + sg;
    GLOAD16(src, (char*)Bb + c * 8192 + w * 1024);
  };
  const int swz = ((kq ^ ((fr >> 1) & 3)) << 4);
  auto ldA = [&](int c, int r) -> bf16x8 {
    return *(const bf16x8*)((const char*)Ab + c * 16384 + r * 64 + swz);
  };
  auto ldB = [&](int c, int r) -> bf16x8 {
    return *(const bf16x8*)((const char*)Bb + c * 8192 + r * 64 + swz);
  };

  f32x4 acc[4][4] = {};
  bf16x8 a[4], b[4];

  const int nt = K >> 5;
#pragma unroll
  for (int tt = 0; tt < 2; ++tt) {
    stageA(tt, 0, tt * 32); stageA(tt, 1, tt * 32); stageB(tt, tt * 32);
  }
  asm volatile("s_waitcnt vmcnt(3)" ::: "memory");
  BARRIER;

  int cur = 0, nxt = 2;
  for (int t = 0; t < nt; ++t) {
#pragma unroll
    for (int mf = 0; mf < 4; ++mf) a[mf] = ldA(cur, wm * 64 + mf * 16 + fr);
#pragma unroll
    for (int nf = 0; nf < 4; ++nf) b[nf] = ldB(cur, wn * 64 + nf * 16 + fr);
    if (t + 2 < nt) {
      stageA(nxt, 0, (t + 2) * 32); stageA(nxt, 1, (t + 2) * 32); stageB(nxt, (t + 2) * 32);
    }
    __builtin_amdgcn_s_setprio(1);
#pragma unroll
    for (int mf = 0; mf < 4; ++mf)
#pragma unroll
      for (int nf = 0; nf < 4; ++nf)
        acc[mf][nf] = __builtin_amdgcn_mfma_f32_16x16x32_bf16(a[mf], b[nf], acc[mf][nf], 0, 0, 0);
    __builtin_amdgcn_s_setprio(0);
    if (t <= nt - 3)      { asm volatile("s_waitcnt vmcnt(3)" ::: "memory"); }
    else if (t == nt - 2) { asm volatile("s_waitcnt vmcnt(0)" ::: "memory"); }
    BARRIER;
    cur = (cur == 2) ? 0 : cur + 1;
    nxt = (nxt == 2) ? 0 : nxt + 1;
  }

#pragma unroll
  for (int nf = 0; nf < 4; ++nf) {
    int col = bn0 + wn * 64 + nf * 16 + fr;
    float bsv = bias[col];
#pragma unroll
    for (int mf = 0; mf < 4; ++mf) {
      int rowb = bm0 + wm * 64 + mf * 16 + kq * 4;
#pragma unroll
      for (int j = 0; j < 4; ++j) {
        int row = rowb + j;
        float v = acc[mf][nf][j] + bsv;
        if (EPI == 1) v = 0.5f * v * (1.0f + erff(v * 0.7071067811865476f));
        if (EPI == 2) {
          ((float*)Cout)[(size_t)row * N + col] = v + resid[(size_t)row * N + col];
        } else {
          ((__hip_bfloat16*)Cout)[(size_t)row * N + col] = __float2bfloat16(v);
        }
      }
    }
  }
}

// ===================== 128x128 GEMM, BK=64, dbuf (FC1) — 2D L2-chunk XCD swizzle =====================
// Per-XCD working set: old 1D swizzle gave 4 rows x 32 cols = A(1MB)+B(8MB) = 9MB >> 4MB L2.
// New: XCD x owns a 16x8 tile region; its 64 co-resident blocks cover an 8x8 square =
// A(2MB)+B(2MB) = 4MB = L2. Bijective: x=orig&7, k=orig>>3; row=(x>>2)*16+(k>>3),
// col=(x&3)*8+(k&7). (Falls back to 1D swizzle for non-32x32 grids.)
template <int EPI>
__global__ __launch_bounds__(512, 4) void gemm128bk64(const __hip_bfloat16* __restrict__ A,
                                                      const __hip_bfloat16* __restrict__ Bt,
                                                      const float* __restrict__ bias,
                                                      const float* __restrict__ resid,
                                                      void* __restrict__ Cout,
                                                      int M, int N, int K) {
  __shared__ __hip_bfloat16 Ab[2][128][64];  // 2 x 16 KB
  __shared__ __hip_bfloat16 Bb[2][128][64];  // 2 x 16 KB
  const int tid = threadIdx.x, lane = tid & 63, w = tid >> 6;
  const int wm = w >> 2, wn = w & 3;  // 2M x 4N waves

  int nbx = gridDim.x, nwg = nbx * gridDim.y;
  int orig = blockIdx.y * nbx + blockIdx.x;
  int bm0, bn0;
  if (nbx == 32 && gridDim.y == 32) {
    int x = orig & 7, k = orig >> 3;
    int row = (x >> 2) * 16 + (k >> 3);
    int col = (x & 3) * 8 + (k & 7);
    bm0 = row * 128; bn0 = col * 128;
  } else {
    int cpx = nwg >> 3;
    int wgid = (orig & 7) * cpx + (orig >> 3);
    bm0 = (wgid / nbx) * 128; bn0 = (wgid % nbx) * 128;
  }

  const int fr = lane & 15, kq = lane >> 4;
  const int srw = lane >> 3;                      // row within 8-row unit
  const int sg = ((lane & 7) ^ (lane >> 3)) * 8;  // inverse-swizzled src col (elems)

  auto stageA = [&](int c, int j, int k0) {
    int u = 2 * w + j;  // 0..15
    const __hip_bfloat16* src = A + (size_t)(bm0 + u * 8 + srw) * K + k0 + sg;
    GLOAD16(src, (char*)Ab + c * 16384 + u * 1024);
  };
  auto stageB = [&](int c, int j, int k0) {
    int u = 2 * w + j;
    const __hip_bfloat16* src = Bt + (size_t)(bn0 + u * 8 + srw) * K + k0 + sg;
    GLOAD16(src, (char*)Bb + c * 16384 + u * 1024);
  };
  auto ldA = [&](int c, int r, int ks) -> bf16x8 {
    int byte = r * 128 + ((ks * 64 + kq * 16) ^ ((r & 7) << 4));
    return *(const bf16x8*)((const char*)Ab + c * 16384 + byte);
  };
  auto ldB = [&](int c, int r, int ks) -> bf16x8 {
    int byte = r * 128 + ((ks * 64 + kq * 16) ^ ((r & 7) << 4));
    return *(const bf16x8*)((const char*)Bb + c * 16384 + byte);
  };

  f32x4 acc[4][2] = {};
  bf16x8 a[4][2], b[2][2];

  const int nt = K >> 6;
  stageA(0, 0, 0);  stageA(0, 1, 0);  stageB(0, 0, 0);  stageB(0, 1, 0);
  stageA(1, 0, 64); stageA(1, 1, 64); stageB(1, 0, 64); stageB(1, 1, 64);
  asm volatile("s_waitcnt vmcnt(4)" ::: "memory");
  BARRIER;

  for (int t = 0; t < nt; ++t) {
    const int cur = t & 1;
#pragma unroll
    for (int mf = 0; mf < 4; ++mf)
#pragma unroll
      for (int ks = 0; ks < 2; ++ks)
        a[mf][ks] = ldA(cur, wm * 64 + mf * 16 + fr, ks);
#pragma unroll
    for (int nf = 0; nf < 2; ++nf)
#pragma unroll
      for (int ks = 0; ks < 2; ++ks)
        b[nf][ks] = ldB(cur, wn * 32 + nf * 16 + fr, ks);
    __builtin_amdgcn_s_setprio(1);
#pragma unroll
    for (int mf = 0; mf < 4; ++mf)
#pragma unroll
      for (int nf = 0; nf < 2; ++nf)
#pragma unroll
        for (int ks = 0; ks < 2; ++ks)
          acc[mf][nf] = __builtin_amdgcn_mfma_f32_16x16x32_bf16(
              a[mf][ks], b[nf][ks], acc[mf][nf], 0, 0, 0);
    __builtin_amdgcn_s_setprio(0);
    BARRIER;
    if (t + 2 < nt) {
      int kn = (t + 2) * 64;
      stageA(cur, 0, kn); stageA(cur, 1, kn); stageB(cur, 0, kn); stageB(cur, 1, kn);
      asm volatile("s_waitcnt vmcnt(4)" ::: "memory");
    } else if (t + 1 < nt) {
      asm volatile("s_waitcnt vmcnt(0)" ::: "memory");
    }
    BARRIER;
  }

#pragma unroll
  for (int nf = 0; nf < 2; ++nf) {
    int col = bn0 + wn * 32 + nf * 16 + fr;
    float bsv = bias[col];
#pragma unroll
    for (int mf = 0; mf < 4; ++mf) {
      int rowb = bm0 + wm * 64 + mf * 16 + kq * 4;
#pragma unroll
      for (int j = 0; j < 4; ++j) {
        int row = rowb + j;
        float v = acc[mf][nf][j] + bsv;
        if (EPI == 1) v = 0.5f * v * (1.0f + erff(v * 0.7071067811865476f));
        if (EPI == 2) {
          ((float*)Cout)[(size_t)row * N + col] = v + resid[(size_t)row * N + col];
        } else {
          ((__hip_bfloat16*)Cout)[(size_t)row * N + col] = __float2bfloat16(v);
        }
      }
    }
  }
}

// ===================== 128x64 GEMM, 8 waves, BK=64, triple-buffered (proj/FC2) =====================
template <int EPI>
__global__ __launch_bounds__(512, 4) void gemm128x64w8(const __hip_bfloat16* __restrict__ A,
                                                       const __hip_bfloat16* __restrict__ Bt,
                                                       const float* __restrict__ bias,
                                                       const float* __restrict__ resid,
                                                       void* __restrict__ Cout,
                                                       int M, int N, int K) {
  __shared__ __hip_bfloat16 Ab[3][128][64];  // 3 x 16 KB
  __shared__ __hip_bfloat16 Bb[3][64][64];   // 3 x 8 KB
  const int tid = threadIdx.x, lane = tid & 63, w = tid >> 6;
  const int wm = w >> 1, wn = w & 1;

  int nbx = gridDim.x, nwg = nbx * gridDim.y;
  int orig = blockIdx.y * nbx + blockIdx.x;
  int cpx = nwg >> 3;
  int wgid = (orig & 7) * cpx + (orig >> 3);
  int bm0 = (wgid / nbx) * 128, bn0 = (wgid % nbx) * 64;

  const int fr = lane & 15, kq = lane >> 4;
  const int srw = lane >> 3;
  const int sg = ((lane & 7) ^ (lane >> 3)) * 8;

  auto stageA = [&](int c, int j, int k0) {
    int u = 2 * w + j;
    const __hip_bfloat16* src = A + (size_t)(bm0 + u * 8 + srw) * K + k0 + sg;
    GLOAD16(src, (char*)Ab + c * 16384 + u * 1024);
  };
  auto stageB = [&](int c, int k0) {
    const __hip_bfloat16* src = Bt + (size_t)(bn0 + w * 8 + srw) * K + k0 + sg;
    GLOAD16(src, (char*)Bb + c * 8192 + w * 1024);
  };
  auto ldA = [&](int c, int r, int ks) -> bf16x8 {
    int byte = r * 128 + ((ks * 64 + kq * 16) ^ ((r & 7) << 4));
    return *(const bf16x8*)((const char*)Ab + c * 16384 + byte);
  };
  auto ldB = [&](int c, int r, int ks) -> bf16x8 {
    int byte = r * 128 + ((ks * 64 + kq * 16) ^ ((r & 7) << 4));
    return *(const bf16x8*)((const char*)Bb + c * 8192 + byte);
  };

  f32x4 acc[2][2] = {};
  bf16x8 a[2][2], b[2][2];

  const int nt = K >> 6;
#pragma unroll
  for (int tt = 0; tt < 2; ++tt) {
    stageA(tt, 0, tt * 64); stageA(tt, 1, tt * 64); stageB(tt, tt * 64);
  }
  asm volatile("s_waitcnt vmcnt(3)" ::: "memory");
  BARRIER;

  int cur = 0, nxt = 2;
  for (int t = 0; t < nt; ++t) {
#pragma unroll
    for (int mf = 0; mf < 2; ++mf)
#pragma unroll
      for (int ks = 0; ks < 2; ++ks)
        a[mf][ks] = ldA(cur, wm * 32 + mf * 16 + fr, ks);
#pragma unroll
    for (int nf = 0; nf < 2; ++nf)
#pragma unroll
      for (int ks = 0; ks < 2; ++ks)
        b[nf][ks] = ldB(cur, wn * 32 + nf * 16 + fr, ks);
    if (t + 2 < nt) {
      stageA(nxt, 0, (t + 2) * 64); stageA(nxt, 1, (t + 2) * 64); stageB(nxt, (t + 2) * 64);
    }
    __builtin_amdgcn_s_setprio(1);
#pragma unroll
    for (int mf = 0; mf < 2; ++mf)
#pragma unroll
      for (int nf = 0; nf < 2; ++nf)
#pragma unroll
        for (int ks = 0; ks < 2; ++ks)
          acc[mf][nf] = __builtin_amdgcn_mfma_f32_16x16x32_bf16(
              a[mf][ks], b[nf][ks], acc[mf][nf], 0, 0, 0);
    __builtin_amdgcn_s_setprio(0);
    if (t <= nt - 3)      { asm volatile("s_waitcnt vmcnt(3)" ::: "memory"); }
    else if (t == nt - 2) { asm volatile("s_waitcnt vmcnt(0)" ::: "memory"); }
    BARRIER;
    cur = (cur == 2) ? 0 : cur + 1;
    nxt = (nxt == 2) ? 0 : nxt + 1;
  }

#pragma unroll
  for (int nf = 0; nf < 2; ++nf) {
    int col = bn0 + wn * 32 + nf * 16 + fr;
    float bsv = bias[col];
#pragma unroll
    for (int mf = 0; mf < 2; ++mf) {
      int rowb = bm0 + wm * 32 + mf * 16 + kq * 4;
#pragma unroll
      for (int j = 0; j < 4; ++j) {
        int row = rowb + j;
        float v = acc[mf][nf][j] + bsv;
        if (EPI == 1) v = 0.5f * v * (1.0f + erff(v * 0.7071067811865476f));
        if (EPI == 2) {
          ((float*)Cout)[(size_t)row * N + col] = v + resid[(size_t)row * N + col];
        } else {
          ((__hip_bfloat16*)Cout)[(size_t)row * N + col] = __float2bfloat16(v);
        }
      }
    }
  }
}

// ---------------- MFMA flash attention, defer-max (unchanged) ----------------
__global__ __launch_bounds__(256) void attn_mfma(const __hip_bfloat16* __restrict__ qkv,
                                                 const __hip_bfloat16* __restrict__ Erb,
                                                 __hip_bfloat16* __restrict__ Y) {
  __shared__ __hip_bfloat16 k_s[64][72];
  __shared__ __hip_bfloat16 er_s[64][72];
  __shared__ __hip_bfloat16 p_s[4][16][72];
  __shared__ __hip_bfloat16 g_s[4][16][132];
  __shared__ __hip_bfloat16 vt_s[64 * 64];

  int bid = blockIdx.x;
  int qi = 15 - (bid >> 6);
  int head = bid & 63;
  int h = head & 15, b = head >> 4;
  int l0 = qi * 64;
  int tid = threadIdx.x, lane = tid & 63, w = tid >> 6;
  const int fr = lane & 15, kq = lane >> 4;

  const __hip_bfloat16* base = qkv + (size_t)b * (LL * 3072) + h * 64;

  bf16x8 qf[2];
  {
    const __hip_bfloat16* q0 = base + (size_t)(l0 + 16 * w + fr) * 3072 + kq * 8;
    qf[0] = *(const bf16x8*)q0;
    qf[1] = *(const bf16x8*)(q0 + 32);
  }

  const int ksr = tid >> 2, ksd = (tid & 3) * 16;
  const __hip_bfloat16* ksrc = base + 1024 + (size_t)ksr * 3072 + ksd;
  const int vc = (tid >> 3) * 2, vd0 = (tid & 7) * 8;
  const __hip_bfloat16* vsrc = base + 2048 + (size_t)vc * 3072 + vd0;
  const int err = tid >> 2, erc = (tid & 3) * 16;

  uint4 kst0, kst1, vst0, vst1;
  uint4 ers0, ers1;
  uint4 ec10, ec11;

  {
    kst0 = *(const uint4*)ksrc; kst1 = *(const uint4*)(ksrc + 8);
    vst0 = *(const uint4*)vsrc; vst1 = *(const uint4*)(vsrc + 3072);
    int m0 = min(max(960 - l0 + err, 0), 1023);
    const __hip_bfloat16* ep0 = Erb + (size_t)m0 * 64 + erc;
    ers0 = *(const uint4*)ep0; ers1 = *(const uint4*)(ep0 + 8);
    if (qi > 0) {
      int m1 = min(max(960 - l0 + 64 + err, 0), 1023);
      const __hip_bfloat16* ep1 = Erb + (size_t)m1 * 64 + erc;
      ec10 = *(const uint4*)ep1; ec11 = *(const uint4*)(ep1 + 8);
    }
  }

  f32x4 oacc[4] = {};
  float m_run[4], s_run[4];
#pragma unroll
  for (int j = 0; j < 4; ++j) { m_run[j] = -1e30f; s_run[j] = 0.f; }

  auto gchunk = [&](int hf) {
#pragma unroll
    for (int g = 0; g < 4; ++g) {
      int cc = 16 * g + fr, kc = kq * 8;
      bf16x8 e0 = *(const bf16x8*)&er_s[cc][kc];
      bf16x8 e1 = *(const bf16x8*)&er_s[cc][kc + 32];
      f32x4 gacc = {};
      gacc = __builtin_amdgcn_mfma_f32_16x16x32_bf16(qf[0], e0, gacc, 0, 0, 0);
      gacc = __builtin_amdgcn_mfma_f32_16x16x32_bf16(qf[1], e1, gacc, 0, 0, 0);
#pragma unroll
      for (int j = 0; j < 4; ++j)
        g_s[w][kq * 4 + j][hf * 64 + 16 * g + fr] = __float2bfloat16(gacc[j]);
    }
  };

  for (int t = 0; t <= qi; ++t) {
    __syncthreads();
    *(uint4*)&k_s[ksr][ksd] = kst0;
    *(uint4*)&k_s[ksr][ksd + 8] = kst1;
    {
      const uint16_t* h0 = (const uint16_t*)&vst0;
      const uint16_t* h1 = (const uint16_t*)&vst1;
#pragma unroll
      for (int j = 0; j < 8; ++j) {
        int d = vd0 + j;
        uint32_t pk = (uint32_t)h0[j] | ((uint32_t)h1[j] << 16);
        uint32_t byte = ((uint32_t)d << 7) + 2u * (uint32_t)vc;
        byte ^= (uint32_t)(((d & 7) ^ (d >> 3)) << 4);
        *(uint32_t*)((char*)vt_s + byte) = pk;
      }
    }
    if (t == 0 || t < qi) {
      *(uint4*)&er_s[err][erc]     = ers0;
      *(uint4*)&er_s[err][erc + 8] = ers1;
    }
    __syncthreads();
    if (t < qi) {
      int c0n = (t + 1) * 64;
      const __hip_bfloat16* kp = ksrc + (size_t)c0n * 3072;
      kst0 = *(const uint4*)kp; kst1 = *(const uint4*)(kp + 8);
      const __hip_bfloat16* vp = vsrc + (size_t)c0n * 3072;
      vst0 = *(const uint4*)vp; vst1 = *(const uint4*)(vp + 3072);
      if (t + 1 < qi) {
        int m = min(960 - l0 + (t + 2) * 64 + err, 1023);
        const __hip_bfloat16* ep = Erb + (size_t)m * 64 + erc;
        ers0 = *(const uint4*)ep; ers1 = *(const uint4*)(ep + 8);
      }
    }
    SCHEDB;

    f32x4 sacc[4] = {};
#pragma unroll
    for (int f = 0; f < 4; ++f) {
      int cc = 16 * f + fr, kc = kq * 8;
      bf16x8 k0 = *(const bf16x8*)&k_s[cc][kc];
      bf16x8 k1 = *(const bf16x8*)&k_s[cc][kc + 32];
      sacc[f] = __builtin_amdgcn_mfma_f32_16x16x32_bf16(qf[0], k0, sacc[f], 0, 0, 0);
      sacc[f] = __builtin_amdgcn_mfma_f32_16x16x32_bf16(qf[1], k1, sacc[f], 0, 0, 0);
    }
    if (t == 0) {
      gchunk(0);
      if (qi > 0) {
        __syncthreads();
        *(uint4*)&er_s[err][erc]     = ec10;
        *(uint4*)&er_s[err][erc + 8] = ec11;
        __syncthreads();
        gchunk(1);
      }
    } else if (t < qi) {
      gchunk((t + 1) & 1);
    }

    float sv[4][4];
#pragma unroll
    for (int f = 0; f < 4; ++f) {
#pragma unroll
      for (int j = 0; j < 4; ++j) {
        int r = kq * 4 + j;
        int c = 16 * f + fr;
        int jj = c - (16 * w + r) + 63;
        float g = __bfloat162float(g_s[w][r][(t * 64 + jj) & 127]);
        float val = (sacc[f][j] + g) * 0.125f;
        if (t == qi && c > 16 * w + r) val = -1e30f;
        sv[f][j] = val;
      }
    }
    float tm[4];
#pragma unroll
    for (int j = 0; j < 4; ++j) {
      float m_ = fmaxf(fmaxf(sv[0][j], sv[1][j]), fmaxf(sv[2][j], sv[3][j]));
      m_ = fmaxf(m_, __shfl_xor(m_, 1));
      m_ = fmaxf(m_, __shfl_xor(m_, 2));
      m_ = fmaxf(m_, __shfl_xor(m_, 4));
      m_ = fmaxf(m_, __shfl_xor(m_, 8));
      tm[j] = m_;
    }
    bool need = (tm[0] > m_run[0] + 8.f) || (tm[1] > m_run[1] + 8.f) ||
                (tm[2] > m_run[2] + 8.f) || (tm[3] > m_run[3] + 8.f);
    float alpha[4];
    if (need) {
#pragma unroll
      for (int j = 0; j < 4; ++j) {
        float nm = fmaxf(m_run[j], tm[j]);
        alpha[j] = __expf(m_run[j] - nm);
        m_run[j] = nm;
      }
    }
#pragma unroll
    for (int f = 0; f < 4; ++f)
#pragma unroll
      for (int j = 0; j < 4; ++j)
        sv[f][j] = __expf(sv[f][j] - m_run[j]);
#pragma unroll
    for (int j = 0; j < 4; ++j) {
      float ps = sv[0][j] + sv[1][j] + sv[2][j] + sv[3][j];
      ps += __shfl_xor(ps, 1); ps += __shfl_xor(ps, 2);
      ps += __shfl_xor(ps, 4); ps += __shfl_xor(ps, 8);
      s_run[j] = (need ? s_run[j] * alpha[j] : s_run[j]) + ps;
    }
    if (need) {
#pragma unroll
      for (int f = 0; f < 4; ++f)
#pragma unroll
        for (int j = 0; j < 4; ++j)
          oacc[f][j] *= alpha[j];
    }
#pragma unroll
    for (int f = 0; f < 4; ++f)
#pragma unroll
      for (int j = 0; j < 4; ++j)
        p_s[w][kq * 4 + j][16 * f + fr] = __float2bfloat16(sv[f][j]);
#pragma unroll
    for (int kk = 0; kk < 2; ++kk) {
      bf16x8 pf = *(const bf16x8*)&p_s[w][fr][kq * 8 + 32 * kk];
#pragma unroll
      for (int f = 0; f < 4; ++f) {
        int d = 16 * f + fr;
        int cc = kq * 8 + 32 * kk;
        uint32_t byte = ((uint32_t)d << 7) + 2u * (uint32_t)cc;
        byte ^= (uint32_t)(((d & 7) ^ (d >> 3)) << 4);
        bf16x8 vf = *(const bf16x8*)((char*)vt_s + byte);
        oacc[f] = __builtin_amdgcn_mfma_f32_16x16x32_bf16(pf, vf, oacc[f], 0, 0, 0);
      }
    }
  }

#pragma unroll
  for (int f = 0; f < 4; ++f)
#pragma unroll
    for (int j = 0; j < 4; ++j) {
      int r = 16 * w + kq * 4 + j;
      int d = 16 * f + fr;
      float o = oacc[f][j] / s_run[j];
      Y[(size_t)(b * LL + l0 + r) * DD + h * 64 + d] = __float2bfloat16(o);
    }
}

// ---------------- launch ----------------
extern "C" void kernel_launch(void* const* d_in, const int* in_sizes, int n_in,
                              void* d_out, int out_size, void* d_ws, size_t ws_size,
                              hipStream_t stream) {
  (void)in_sizes; (void)n_in; (void)out_size; (void)ws_size;
  const float* x     = (const float*)d_in[0];
  const float* ln1w  = (const float*)d_in[1];
  const float* ln1b  = (const float*)d_in[2];
  const float* Wqkv  = (const float*)d_in[3];
  const float* bqkv  = (const float*)d_in[4];
  const float* Wproj = (const float*)d_in[5];
  const float* bproj = (const float*)d_in[6];
  const float* Er    = (const float*)d_in[7];
  const float* ln2w  = (const float*)d_in[8];
  const float* ln2b  = (const float*)d_in[9];
  const float* Wfc   = (const float*)d_in[10];
  const float* bfc   = (const float*)d_in[11];
  const float* Wfc2  = (const float*)d_in[12];
  const float* bfc2  = (const float*)d_in[13];
  float* out = (float*)d_out;

  char* ws = (char*)d_ws;
  const size_t MB = 1ull << 20;
  __hip_bfloat16* h1    = (__hip_bfloat16*)(ws + 0);        // 8 MB
  __hip_bfloat16* qkvb  = (__hip_bfloat16*)(ws + 8 * MB);   // 24 MB
  __hip_bfloat16* mbuf  = (__hip_bfloat16*)(ws + 0);        // 32 MB (aliases h1+qkvb)
  __hip_bfloat16* yb    = (__hip_bfloat16*)(ws + 32 * MB);  // 8 MB
  __hip_bfloat16* h2    = (__hip_bfloat16*)(ws + 32 * MB);  // 8 MB (aliases yb)
  float*          x2    = (float*)(ws + 40 * MB);           // 16 MB
  __hip_bfloat16* Wqkvt = (__hip_bfloat16*)(ws + 56 * MB);  // 6 MB
  __hip_bfloat16* Erb   = (__hip_bfloat16*)(ws + 62 * MB);  // 128 KB
  __hip_bfloat16* Wprojt= (__hip_bfloat16*)(ws + 63 * MB);  // 2 MB
  __hip_bfloat16* Wfct  = (__hip_bfloat16*)(ws + 66 * MB);  // 8 MB
  __hip_bfloat16* Wfc2t = (__hip_bfloat16*)(ws + 75 * MB);  // 8 MB

  dim3 blk(256);

  prep_weights<<<dim3(16448), blk, 0, stream>>>(Wqkv, Wproj, Wfc, Wfc2, Er,
                                                x, ln1w, ln1b,
                                                Wqkvt, Wprojt, Wfct, Wfc2t, Erb, h1);

  gemm256x128<0><<<dim3(3072 / 128, 4096 / 256), dim3(512), 0, stream>>>(
      h1, Wqkvt, bqkv, nullptr, qkvb, 4096, 3072, 1024);

  attn_mfma<<<dim3(1024), blk, 0, stream>>>(qkvb, Erb, yb);

  gemm128x64w8<2><<<dim3(1024 / 64, 4096 / 128), dim3(512), 0, stream>>>(
      yb, Wprojt, bproj, x, x2, 4096, 1024, 1024);

  ln_kernel<<<4096, blk, 0, stream>>>(x2, ln2w, ln2b, h2);

  gemm128bk64<1><<<dim3(4096 / 128, 4096 / 128), dim3(512), 0, stream>>>(
      h2, Wfct, bfc, nullptr, mbuf, 4096, 4096, 1024);

  gemm128x64w8<2><<<dim3(1024 / 64, 4096 / 128), dim3(512), 0, stream>>>(
      mbuf, Wfc2t, bfc2, x2, out, 4096, 1024, 4096);
}

// Round 25
// 215.247 us; speedup vs baseline: 1.0311x; 1.0072x over previous
//
#include <hip/hip_runtime.h>
#include <hip/hip_bf16.h>
#include <math.h>

typedef __attribute__((ext_vector_type(8))) __bf16 bf16x8;
typedef __attribute__((ext_vector_type(4))) float f32x4;

#define LL 1024
#define DD 1024
#define HH 16

#define GLOAD16(g, l)                                              \
  __builtin_amdgcn_global_load_lds(                                \
      (const __attribute__((address_space(1))) void*)(g),          \
      (__attribute__((address_space(3))) void*)(l), 16, 0, 0)

#define FENCE asm volatile("" ::: "memory")
#define SCHEDB __builtin_amdgcn_sched_barrier(0)
#define BARRIER do { FENCE; __builtin_amdgcn_s_barrier(); FENCE; } while (0)

// ---------------- merged prep: 4 transposes + Er cvt + LN1 in ONE dispatch ----------------
__global__ __launch_bounds__(256) void prep_weights(const float* __restrict__ Wqkv,
                                                    const float* __restrict__ Wproj,
                                                    const float* __restrict__ Wfc,
                                                    const float* __restrict__ Wfc2,
                                                    const float* __restrict__ Er,
                                                    const float* __restrict__ X,
                                                    const float* __restrict__ ln1w,
                                                    const float* __restrict__ ln1b,
                                                    __hip_bfloat16* __restrict__ Wqkvt,
                                                    __hip_bfloat16* __restrict__ Wprojt,
                                                    __hip_bfloat16* __restrict__ Wfct,
                                                    __hip_bfloat16* __restrict__ Wfc2t,
                                                    __hip_bfloat16* __restrict__ Erb,
                                                    __hip_bfloat16* __restrict__ h1) {
  int bid = blockIdx.x;
  int tx = threadIdx.x;
  if (bid >= 12352) {  // ---- LN1 row ----
    int row = bid - 12352;
    const float* xr = X + (size_t)row * DD;
    float4 v = *(const float4*)&xr[tx * 4];
    float s = v.x + v.y + v.z + v.w;
    float s2 = v.x * v.x + v.y * v.y + v.z * v.z + v.w * v.w;
#pragma unroll
    for (int m = 1; m < 64; m <<= 1) {
      s += __shfl_xor(s, m);
      s2 += __shfl_xor(s2, m);
    }
    __shared__ float ps[4], ps2[4];
    int wv_ = tx >> 6, lane = tx & 63;
    if (lane == 0) { ps[wv_] = s; ps2[wv_] = s2; }
    __syncthreads();
    float ts = ps[0] + ps[1] + ps[2] + ps[3];
    float ts2 = ps2[0] + ps2[1] + ps2[2] + ps2[3];
    float mu = ts * (1.0f / DD);
    float var = ts2 * (1.0f / DD) - mu * mu;
    float rs = rsqrtf(var + 1e-5f);
    float4 wv = *(const float4*)&ln1w[tx * 4];
    float4 bv = *(const float4*)&ln1b[tx * 4];
    __hip_bfloat16 o[4];
    o[0] = __float2bfloat16((v.x - mu) * rs * wv.x + bv.x);
    o[1] = __float2bfloat16((v.y - mu) * rs * wv.y + bv.y);
    o[2] = __float2bfloat16((v.z - mu) * rs * wv.z + bv.z);
    o[3] = __float2bfloat16((v.w - mu) * rs * wv.w + bv.w);
    *(uint2*)&h1[(size_t)row * DD + tx * 4] = *(const uint2*)o;
    return;
  }
  if (bid >= 12288) {  // ---- cvt_er ----
    int i = (bid - 12288) * 256 + tx;
    float4 v = *(const float4*)&Er[(size_t)i * 4];
    __hip_bfloat16 o[4];
    o[0] = __float2bfloat16(v.x); o[1] = __float2bfloat16(v.y);
    o[2] = __float2bfloat16(v.z); o[3] = __float2bfloat16(v.w);
    *(uint2*)&Erb[(size_t)i * 4] = *(const uint2*)o;
    return;
  }
  const float* W; __hip_bfloat16* Wt; int R, C, local;
  if (bid < 3072)      { W = Wqkv;  Wt = Wqkvt;  R = 1024; C = 3072; local = bid; }
  else if (bid < 4096) { W = Wproj; Wt = Wprojt; R = 1024; C = 1024; local = bid - 3072; }
  else if (bid < 8192) { W = Wfc;   Wt = Wfct;   R = 1024; C = 4096; local = bid - 4096; }
  else                 { W = Wfc2;  Wt = Wfc2t;  R = 4096; C = 1024; local = bid - 8192; }
  int nbx = C / 32;
  int r0 = (local / nbx) * 32, c0 = (local % nbx) * 32;
  __shared__ float tile[32][33];
  int r = tx >> 3, c4 = (tx & 7) * 4;
  float4 v = *(const float4*)&W[(size_t)(r0 + r) * C + c0 + c4];
  tile[r][c4 + 0] = v.x; tile[r][c4 + 1] = v.y;
  tile[r][c4 + 2] = v.z; tile[r][c4 + 3] = v.w;
  __syncthreads();
  int c = tx >> 3, r4 = (tx & 7) * 4;
  __hip_bfloat16 o[4];
#pragma unroll
  for (int j = 0; j < 4; ++j) o[j] = __float2bfloat16(tile[r4 + j][c]);
  *(uint2*)&Wt[(size_t)(c0 + c) * R + r0 + r4] = *(const uint2*)o;
}

// ---------------- layernorm (fp32 in -> bf16 out) ----------------
__global__ __launch_bounds__(256) void ln_kernel(const float* __restrict__ X,
                                                 const float* __restrict__ w,
                                                 const float* __restrict__ b,
                                                 __hip_bfloat16* __restrict__ out) {
  int row = blockIdx.x;
  int tid = threadIdx.x;
  const float* xr = X + (size_t)row * DD;
  float4 v = *(const float4*)&xr[tid * 4];
  float s = v.x + v.y + v.z + v.w;
  float s2 = v.x * v.x + v.y * v.y + v.z * v.z + v.w * v.w;
#pragma unroll
  for (int m = 1; m < 64; m <<= 1) {
    s += __shfl_xor(s, m);
    s2 += __shfl_xor(s2, m);
  }
  __shared__ float ps[4], ps2[4];
  int wv_ = tid >> 6, lane = tid & 63;
  if (lane == 0) { ps[wv_] = s; ps2[wv_] = s2; }
  __syncthreads();
  float ts = ps[0] + ps[1] + ps[2] + ps[3];
  float ts2 = ps2[0] + ps2[1] + ps2[2] + ps2[3];
  float mu = ts * (1.0f / DD);
  float var = ts2 * (1.0f / DD) - mu * mu;
  float rs = rsqrtf(var + 1e-5f);
  float4 wv = *(const float4*)&w[tid * 4];
  float4 bv = *(const float4*)&b[tid * 4];
  __hip_bfloat16 o[4];
  o[0] = __float2bfloat16((v.x - mu) * rs * wv.x + bv.x);
  o[1] = __float2bfloat16((v.y - mu) * rs * wv.y + bv.y);
  o[2] = __float2bfloat16((v.z - mu) * rs * wv.z + bv.z);
  o[3] = __float2bfloat16((v.w - mu) * rs * wv.w + bv.w);
  *(uint2*)&out[(size_t)row * DD + tid * 4] = *(const uint2*)o;
}

// ===================== 256x128 GEMM, triple-buffered gload_lds (QKV) =====================
// 2D L2-chunk XCD swizzle for the 24x16 grid: 8 XCDs as 4x2 regions of 4Mrows x 12Ncols
// -> per-XCD working set A(2MB)+B(1.5MB) = 3.5MB <= 4MB L2 (old 1D: 7MB, thrash).
template <int EPI>
__global__ __launch_bounds__(512, 4) void gemm256x128(const __hip_bfloat16* __restrict__ A,
                                                      const __hip_bfloat16* __restrict__ Bt,
                                                      const float* __restrict__ bias,
                                                      const float* __restrict__ resid,
                                                      void* __restrict__ Cout,
                                                      int M, int N, int K) {
  __shared__ __hip_bfloat16 Ab[3][256][32];  // 3 x 16 KB
  __shared__ __hip_bfloat16 Bb[3][128][32];  // 3 x 8 KB
  const int tid = threadIdx.x, lane = tid & 63, w = tid >> 6;
  const int wm = w >> 1, wn = w & 1;  // 4M x 2N waves

  int nbx = gridDim.x, nwg = nbx * gridDim.y;
  int orig = blockIdx.y * nbx + blockIdx.x;
  int bm0, bn0;
  if (nbx == 24 && gridDim.y == 16) {
    // 2D chunk: x = XCD, k = 0..47; XCD (xr,xc) owns rows xr*4..+3, cols xc*12..+11
    int x = orig & 7, k = orig >> 3;
    int xr = x >> 1, xc = x & 1;
    int row = xr * 4 + (k & 3);
    int col = xc * 12 + (k >> 2);
    bm0 = row * 256; bn0 = col * 128;
  } else {
    int cpx = nwg >> 3;
    int wgid = (orig & 7) * cpx + (orig >> 3);
    bm0 = (wgid / nbx) * 256; bn0 = (wgid % nbx) * 128;
  }

  const int fr = lane & 15, kq = lane >> 4;
  const int sg = ((lane & 3) ^ ((lane >> 3) & 3)) * 8;  // inverse-swizzled src col
  const int srw = lane >> 2;

  auto stageA = [&](int c, int g, int k0) {
    int u = w * 2 + g;
    const __hip_bfloat16* src = A + (size_t)(bm0 + u * 16 + srw) * K + k0 + sg;
    GLOAD16(src, (char*)Ab + c * 16384 + u * 1024);
  };
  auto stageB = [&](int c, int k0) {
    const __hip_bfloat16* src = Bt + (size_t)(bn0 + w * 16 + srw) * K + k0 + sg;
    GLOAD16(src, (char*)Bb + c * 8192 + w * 1024);
  };
  const int swz = ((kq ^ ((fr >> 1) & 3)) << 4);
  auto ldA = [&](int c, int r) -> bf16x8 {
    return *(const bf16x8*)((const char*)Ab + c * 16384 + r * 64 + swz);
  };
  auto ldB = [&](int c, int r) -> bf16x8 {
    return *(const bf16x8*)((const char*)Bb + c * 8192 + r * 64 + swz);
  };

  f32x4 acc[4][4] = {};
  bf16x8 a[4], b[4];

  const int nt = K >> 5;
#pragma unroll
  for (int tt = 0; tt < 2; ++tt) {
    stageA(tt, 0, tt * 32); stageA(tt, 1, tt * 32); stageB(tt, tt * 32);
  }
  asm volatile("s_waitcnt vmcnt(3)" ::: "memory");
  BARRIER;

  int cur = 0, nxt = 2;
  for (int t = 0; t < nt; ++t) {
#pragma unroll
    for (int mf = 0; mf < 4; ++mf) a[mf] = ldA(cur, wm * 64 + mf * 16 + fr);
#pragma unroll
    for (int nf = 0; nf < 4; ++nf) b[nf] = ldB(cur, wn * 64 + nf * 16 + fr);
    if (t + 2 < nt) {
      stageA(nxt, 0, (t + 2) * 32); stageA(nxt, 1, (t + 2) * 32); stageB(nxt, (t + 2) * 32);
    }
    __builtin_amdgcn_s_setprio(1);
#pragma unroll
    for (int mf = 0; mf < 4; ++mf)
#pragma unroll
      for (int nf = 0; nf < 4; ++nf)
        acc[mf][nf] = __builtin_amdgcn_mfma_f32_16x16x32_bf16(a[mf], b[nf], acc[mf][nf], 0, 0, 0);
    __builtin_amdgcn_s_setprio(0);
    if (t <= nt - 3)      { asm volatile("s_waitcnt vmcnt(3)" ::: "memory"); }
    else if (t == nt - 2) { asm volatile("s_waitcnt vmcnt(0)" ::: "memory"); }
    BARRIER;
    cur = (cur == 2) ? 0 : cur + 1;
    nxt = (nxt == 2) ? 0 : nxt + 1;
  }

#pragma unroll
  for (int nf = 0; nf < 4; ++nf) {
    int col = bn0 + wn * 64 + nf * 16 + fr;
    float bsv = bias[col];
#pragma unroll
    for (int mf = 0; mf < 4; ++mf) {
      int rowb = bm0 + wm * 64 + mf * 16 + kq * 4;
#pragma unroll
      for (int j = 0; j < 4; ++j) {
        int row = rowb + j;
        float v = acc[mf][nf][j] + bsv;
        if (EPI == 1) v = 0.5f * v * (1.0f + erff(v * 0.7071067811865476f));
        if (EPI == 2) {
          ((float*)Cout)[(size_t)row * N + col] = v + resid[(size_t)row * N + col];
        } else {
          ((__hip_bfloat16*)Cout)[(size_t)row * N + col] = __float2bfloat16(v);
        }
      }
    }
  }
}

// ===================== 128x128 GEMM, BK=64, dbuf (FC1) — 2D L2-chunk XCD swizzle =====================
template <int EPI>
__global__ __launch_bounds__(512, 4) void gemm128bk64(const __hip_bfloat16* __restrict__ A,
                                                      const __hip_bfloat16* __restrict__ Bt,
                                                      const float* __restrict__ bias,
                                                      const float* __restrict__ resid,
                                                      void* __restrict__ Cout,
                                                      int M, int N, int K) {
  __shared__ __hip_bfloat16 Ab[2][128][64];  // 2 x 16 KB
  __shared__ __hip_bfloat16 Bb[2][128][64];  // 2 x 16 KB
  const int tid = threadIdx.x, lane = tid & 63, w = tid >> 6;
  const int wm = w >> 2, wn = w & 3;  // 2M x 4N waves

  int nbx = gridDim.x, nwg = nbx * gridDim.y;
  int orig = blockIdx.y * nbx + blockIdx.x;
  int bm0, bn0;
  if (nbx == 32 && gridDim.y == 32) {
    int x = orig & 7, k = orig >> 3;
    int row = (x >> 2) * 16 + (k >> 3);
    int col = (x & 3) * 8 + (k & 7);
    bm0 = row * 128; bn0 = col * 128;
  } else {
    int cpx = nwg >> 3;
    int wgid = (orig & 7) * cpx + (orig >> 3);
    bm0 = (wgid / nbx) * 128; bn0 = (wgid % nbx) * 128;
  }

  const int fr = lane & 15, kq = lane >> 4;
  const int srw = lane >> 3;                      // row within 8-row unit
  const int sg = ((lane & 7) ^ (lane >> 3)) * 8;  // inverse-swizzled src col (elems)

  auto stageA = [&](int c, int j, int k0) {
    int u = 2 * w + j;  // 0..15
    const __hip_bfloat16* src = A + (size_t)(bm0 + u * 8 + srw) * K + k0 + sg;
    GLOAD16(src, (char*)Ab + c * 16384 + u * 1024);
  };
  auto stageB = [&](int c, int j, int k0) {
    int u = 2 * w + j;
    const __hip_bfloat16* src = Bt + (size_t)(bn0 + u * 8 + srw) * K + k0 + sg;
    GLOAD16(src, (char*)Bb + c * 16384 + u * 1024);
  };
  auto ldA = [&](int c, int r, int ks) -> bf16x8 {
    int byte = r * 128 + ((ks * 64 + kq * 16) ^ ((r & 7) << 4));
    return *(const bf16x8*)((const char*)Ab + c * 16384 + byte);
  };
  auto ldB = [&](int c, int r, int ks) -> bf16x8 {
    int byte = r * 128 + ((ks * 64 + kq * 16) ^ ((r & 7) << 4));
    return *(const bf16x8*)((const char*)Bb + c * 16384 + byte);
  };

  f32x4 acc[4][2] = {};
  bf16x8 a[4][2], b[2][2];

  const int nt = K >> 6;
  stageA(0, 0, 0);  stageA(0, 1, 0);  stageB(0, 0, 0);  stageB(0, 1, 0);
  stageA(1, 0, 64); stageA(1, 1, 64); stageB(1, 0, 64); stageB(1, 1, 64);
  asm volatile("s_waitcnt vmcnt(4)" ::: "memory");
  BARRIER;

  for (int t = 0; t < nt; ++t) {
    const int cur = t & 1;
#pragma unroll
    for (int mf = 0; mf < 4; ++mf)
#pragma unroll
      for (int ks = 0; ks < 2; ++ks)
        a[mf][ks] = ldA(cur, wm * 64 + mf * 16 + fr, ks);
#pragma unroll
    for (int nf = 0; nf < 2; ++nf)
#pragma unroll
      for (int ks = 0; ks < 2; ++ks)
        b[nf][ks] = ldB(cur, wn * 32 + nf * 16 + fr, ks);
    __builtin_amdgcn_s_setprio(1);
#pragma unroll
    for (int mf = 0; mf < 4; ++mf)
#pragma unroll
      for (int nf = 0; nf < 2; ++nf)
#pragma unroll
        for (int ks = 0; ks < 2; ++ks)
          acc[mf][nf] = __builtin_amdgcn_mfma_f32_16x16x32_bf16(
              a[mf][ks], b[nf][ks], acc[mf][nf], 0, 0, 0);
    __builtin_amdgcn_s_setprio(0);
    BARRIER;
    if (t + 2 < nt) {
      int kn = (t + 2) * 64;
      stageA(cur, 0, kn); stageA(cur, 1, kn); stageB(cur, 0, kn); stageB(cur, 1, kn);
      asm volatile("s_waitcnt vmcnt(4)" ::: "memory");
    } else if (t + 1 < nt) {
      asm volatile("s_waitcnt vmcnt(0)" ::: "memory");
    }
    BARRIER;
  }

#pragma unroll
  for (int nf = 0; nf < 2; ++nf) {
    int col = bn0 + wn * 32 + nf * 16 + fr;
    float bsv = bias[col];
#pragma unroll
    for (int mf = 0; mf < 4; ++mf) {
      int rowb = bm0 + wm * 64 + mf * 16 + kq * 4;
#pragma unroll
      for (int j = 0; j < 4; ++j) {
        int row = rowb + j;
        float v = acc[mf][nf][j] + bsv;
        if (EPI == 1) v = 0.5f * v * (1.0f + erff(v * 0.7071067811865476f));
        if (EPI == 2) {
          ((float*)Cout)[(size_t)row * N + col] = v + resid[(size_t)row * N + col];
        } else {
          ((__hip_bfloat16*)Cout)[(size_t)row * N + col] = __float2bfloat16(v);
        }
      }
    }
  }
}

// ===================== 128x64 GEMM, 8 waves, BK=64, triple-buffered (proj/FC2) =====================
template <int EPI>
__global__ __launch_bounds__(512, 4) void gemm128x64w8(const __hip_bfloat16* __restrict__ A,
                                                       const __hip_bfloat16* __restrict__ Bt,
                                                       const float* __restrict__ bias,
                                                       const float* __restrict__ resid,
                                                       void* __restrict__ Cout,
                                                       int M, int N, int K) {
  __shared__ __hip_bfloat16 Ab[3][128][64];  // 3 x 16 KB
  __shared__ __hip_bfloat16 Bb[3][64][64];   // 3 x 8 KB
  const int tid = threadIdx.x, lane = tid & 63, w = tid >> 6;
  const int wm = w >> 1, wn = w & 1;

  int nbx = gridDim.x, nwg = nbx * gridDim.y;
  int orig = blockIdx.y * nbx + blockIdx.x;
  int cpx = nwg >> 3;
  int wgid = (orig & 7) * cpx + (orig >> 3);
  int bm0 = (wgid / nbx) * 128, bn0 = (wgid % nbx) * 64;

  const int fr = lane & 15, kq = lane >> 4;
  const int srw = lane >> 3;
  const int sg = ((lane & 7) ^ (lane >> 3)) * 8;

  auto stageA = [&](int c, int j, int k0) {
    int u = 2 * w + j;
    const __hip_bfloat16* src = A + (size_t)(bm0 + u * 8 + srw) * K + k0 + sg;
    GLOAD16(src, (char*)Ab + c * 16384 + u * 1024);
  };
  auto stageB = [&](int c, int k0) {
    const __hip_bfloat16* src = Bt + (size_t)(bn0 + w * 8 + srw) * K + k0 + sg;
    GLOAD16(src, (char*)Bb + c * 8192 + w * 1024);
  };
  auto ldA = [&](int c, int r, int ks) -> bf16x8 {
    int byte = r * 128 + ((ks * 64 + kq * 16) ^ ((r & 7) << 4));
    return *(const bf16x8*)((const char*)Ab + c * 16384 + byte);
  };
  auto ldB = [&](int c, int r, int ks) -> bf16x8 {
    int byte = r * 128 + ((ks * 64 + kq * 16) ^ ((r & 7) << 4));
    return *(const bf16x8*)((const char*)Bb + c * 8192 + byte);
  };

  f32x4 acc[2][2] = {};
  bf16x8 a[2][2], b[2][2];

  const int nt = K >> 6;
#pragma unroll
  for (int tt = 0; tt < 2; ++tt) {
    stageA(tt, 0, tt * 64); stageA(tt, 1, tt * 64); stageB(tt, tt * 64);
  }
  asm volatile("s_waitcnt vmcnt(3)" ::: "memory");
  BARRIER;

  int cur = 0, nxt = 2;
  for (int t = 0; t < nt; ++t) {
#pragma unroll
    for (int mf = 0; mf < 2; ++mf)
#pragma unroll
      for (int ks = 0; ks < 2; ++ks)
        a[mf][ks] = ldA(cur, wm * 32 + mf * 16 + fr, ks);
#pragma unroll
    for (int nf = 0; nf < 2; ++nf)
#pragma unroll
      for (int ks = 0; ks < 2; ++ks)
        b[nf][ks] = ldB(cur, wn * 32 + nf * 16 + fr, ks);
    if (t + 2 < nt) {
      stageA(nxt, 0, (t + 2) * 64); stageA(nxt, 1, (t + 2) * 64); stageB(nxt, (t + 2) * 64);
    }
    __builtin_amdgcn_s_setprio(1);
#pragma unroll
    for (int mf = 0; mf < 2; ++mf)
#pragma unroll
      for (int nf = 0; nf < 2; ++nf)
#pragma unroll
        for (int ks = 0; ks < 2; ++ks)
          acc[mf][nf] = __builtin_amdgcn_mfma_f32_16x16x32_bf16(
              a[mf][ks], b[nf][ks], acc[mf][nf], 0, 0, 0);
    __builtin_amdgcn_s_setprio(0);
    if (t <= nt - 3)      { asm volatile("s_waitcnt vmcnt(3)" ::: "memory"); }
    else if (t == nt - 2) { asm volatile("s_waitcnt vmcnt(0)" ::: "memory"); }
    BARRIER;
    cur = (cur == 2) ? 0 : cur + 1;
    nxt = (nxt == 2) ? 0 : nxt + 1;
  }

#pragma unroll
  for (int nf = 0; nf < 2; ++nf) {
    int col = bn0 + wn * 32 + nf * 16 + fr;
    float bsv = bias[col];
#pragma unroll
    for (int mf = 0; mf < 2; ++mf) {
      int rowb = bm0 + wm * 32 + mf * 16 + kq * 4;
#pragma unroll
      for (int j = 0; j < 4; ++j) {
        int row = rowb + j;
        float v = acc[mf][nf][j] + bsv;
        if (EPI == 1) v = 0.5f * v * (1.0f + erff(v * 0.7071067811865476f));
        if (EPI == 2) {
          ((float*)Cout)[(size_t)row * N + col] = v + resid[(size_t)row * N + col];
        } else {
          ((__hip_bfloat16*)Cout)[(size_t)row * N + col] = __float2bfloat16(v);
        }
      }
    }
  }
}

// ---------------- MFMA flash attention, defer-max (unchanged) ----------------
__global__ __launch_bounds__(256) void attn_mfma(const __hip_bfloat16* __restrict__ qkv,
                                                 const __hip_bfloat16* __restrict__ Erb,
                                                 __hip_bfloat16* __restrict__ Y) {
  __shared__ __hip_bfloat16 k_s[64][72];
  __shared__ __hip_bfloat16 er_s[64][72];
  __shared__ __hip_bfloat16 p_s[4][16][72];
  __shared__ __hip_bfloat16 g_s[4][16][132];
  __shared__ __hip_bfloat16 vt_s[64 * 64];

  int bid = blockIdx.x;
  int qi = 15 - (bid >> 6);
  int head = bid & 63;
  int h = head & 15, b = head >> 4;
  int l0 = qi * 64;
  int tid = threadIdx.x, lane = tid & 63, w = tid >> 6;
  const int fr = lane & 15, kq = lane >> 4;

  const __hip_bfloat16* base = qkv + (size_t)b * (LL * 3072) + h * 64;

  bf16x8 qf[2];
  {
    const __hip_bfloat16* q0 = base + (size_t)(l0 + 16 * w + fr) * 3072 + kq * 8;
    qf[0] = *(const bf16x8*)q0;
    qf[1] = *(const bf16x8*)(q0 + 32);
  }

  const int ksr = tid >> 2, ksd = (tid & 3) * 16;
  const __hip_bfloat16* ksrc = base + 1024 + (size_t)ksr * 3072 + ksd;
  const int vc = (tid >> 3) * 2, vd0 = (tid & 7) * 8;
  const __hip_bfloat16* vsrc = base + 2048 + (size_t)vc * 3072 + vd0;
  const int err = tid >> 2, erc = (tid & 3) * 16;

  uint4 kst0, kst1, vst0, vst1;
  uint4 ers0, ers1;
  uint4 ec10, ec11;

  {
    kst0 = *(const uint4*)ksrc; kst1 = *(const uint4*)(ksrc + 8);
    vst0 = *(const uint4*)vsrc; vst1 = *(const uint4*)(vsrc + 3072);
    int m0 = min(max(960 - l0 + err, 0), 1023);
    const __hip_bfloat16* ep0 = Erb + (size_t)m0 * 64 + erc;
    ers0 = *(const uint4*)ep0; ers1 = *(const uint4*)(ep0 + 8);
    if (qi > 0) {
      int m1 = min(max(960 - l0 + 64 + err, 0), 1023);
      const __hip_bfloat16* ep1 = Erb + (size_t)m1 * 64 + erc;
      ec10 = *(const uint4*)ep1; ec11 = *(const uint4*)(ep1 + 8);
    }
  }

  f32x4 oacc[4] = {};
  float m_run[4], s_run[4];
#pragma unroll
  for (int j = 0; j < 4; ++j) { m_run[j] = -1e30f; s_run[j] = 0.f; }

  auto gchunk = [&](int hf) {
#pragma unroll
    for (int g = 0; g < 4; ++g) {
      int cc = 16 * g + fr, kc = kq * 8;
      bf16x8 e0 = *(const bf16x8*)&er_s[cc][kc];
      bf16x8 e1 = *(const bf16x8*)&er_s[cc][kc + 32];
      f32x4 gacc = {};
      gacc = __builtin_amdgcn_mfma_f32_16x16x32_bf16(qf[0], e0, gacc, 0, 0, 0);
      gacc = __builtin_amdgcn_mfma_f32_16x16x32_bf16(qf[1], e1, gacc, 0, 0, 0);
#pragma unroll
      for (int j = 0; j < 4; ++j)
        g_s[w][kq * 4 + j][hf * 64 + 16 * g + fr] = __float2bfloat16(gacc[j]);
    }
  };

  for (int t = 0; t <= qi; ++t) {
    __syncthreads();
    *(uint4*)&k_s[ksr][ksd] = kst0;
    *(uint4*)&k_s[ksr][ksd + 8] = kst1;
    {
      const uint16_t* h0 = (const uint16_t*)&vst0;
      const uint16_t* h1 = (const uint16_t*)&vst1;
#pragma unroll
      for (int j = 0; j < 8; ++j) {
        int d = vd0 + j;
        uint32_t pk = (uint32_t)h0[j] | ((uint32_t)h1[j] << 16);
        uint32_t byte = ((uint32_t)d << 7) + 2u * (uint32_t)vc;
        byte ^= (uint32_t)(((d & 7) ^ (d >> 3)) << 4);
        *(uint32_t*)((char*)vt_s + byte) = pk;
      }
    }
    if (t == 0 || t < qi) {
      *(uint4*)&er_s[err][erc]     = ers0;
      *(uint4*)&er_s[err][erc + 8] = ers1;
    }
    __syncthreads();
    if (t < qi) {
      int c0n = (t + 1) * 64;
      const __hip_bfloat16* kp = ksrc + (size_t)c0n * 3072;
      kst0 = *(const uint4*)kp; kst1 = *(const uint4*)(kp + 8);
      const __hip_bfloat16* vp = vsrc + (size_t)c0n * 3072;
      vst0 = *(const uint4*)vp; vst1 = *(const uint4*)(vp + 3072);
      if (t + 1 < qi) {
        int m = min(960 - l0 + (t + 2) * 64 + err, 1023);
        const __hip_bfloat16* ep = Erb + (size_t)m * 64 + erc;
        ers0 = *(const uint4*)ep; ers1 = *(const uint4*)(ep + 8);
      }
    }
    SCHEDB;

    f32x4 sacc[4] = {};
#pragma unroll
    for (int f = 0; f < 4; ++f) {
      int cc = 16 * f + fr, kc = kq * 8;
      bf16x8 k0 = *(const bf16x8*)&k_s[cc][kc];
      bf16x8 k1 = *(const bf16x8*)&k_s[cc][kc + 32];
      sacc[f] = __builtin_amdgcn_mfma_f32_16x16x32_bf16(qf[0], k0, sacc[f], 0, 0, 0);
      sacc[f] = __builtin_amdgcn_mfma_f32_16x16x32_bf16(qf[1], k1, sacc[f], 0, 0, 0);
    }
    if (t == 0) {
      gchunk(0);
      if (qi > 0) {
        __syncthreads();
        *(uint4*)&er_s[err][erc]     = ec10;
        *(uint4*)&er_s[err][erc + 8] = ec11;
        __syncthreads();
        gchunk(1);
      }
    } else if (t < qi) {
      gchunk((t + 1) & 1);
    }

    float sv[4][4];
#pragma unroll
    for (int f = 0; f < 4; ++f) {
#pragma unroll
      for (int j = 0; j < 4; ++j) {
        int r = kq * 4 + j;
        int c = 16 * f + fr;
        int jj = c - (16 * w + r) + 63;
        float g = __bfloat162float(g_s[w][r][(t * 64 + jj) & 127]);
        float val = (sacc[f][j] + g) * 0.125f;
        if (t == qi && c > 16 * w + r) val = -1e30f;
        sv[f][j] = val;
      }
    }
    float tm[4];
#pragma unroll
    for (int j = 0; j < 4; ++j) {
      float m_ = fmaxf(fmaxf(sv[0][j], sv[1][j]), fmaxf(sv[2][j], sv[3][j]));
      m_ = fmaxf(m_, __shfl_xor(m_, 1));
      m_ = fmaxf(m_, __shfl_xor(m_, 2));
      m_ = fmaxf(m_, __shfl_xor(m_, 4));
      m_ = fmaxf(m_, __shfl_xor(m_, 8));
      tm[j] = m_;
    }
    bool need = (tm[0] > m_run[0] + 8.f) || (tm[1] > m_run[1] + 8.f) ||
                (tm[2] > m_run[2] + 8.f) || (tm[3] > m_run[3] + 8.f);
    float alpha[4];
    if (need) {
#pragma unroll
      for (int j = 0; j < 4; ++j) {
        float nm = fmaxf(m_run[j], tm[j]);
        alpha[j] = __expf(m_run[j] - nm);
        m_run[j] = nm;
      }
    }
#pragma unroll
    for (int f = 0; f < 4; ++f)
#pragma unroll
      for (int j = 0; j < 4; ++j)
        sv[f][j] = __expf(sv[f][j] - m_run[j]);
#pragma unroll
    for (int j = 0; j < 4; ++j) {
      float ps = sv[0][j] + sv[1][j] + sv[2][j] + sv[3][j];
      ps += __shfl_xor(ps, 1); ps += __shfl_xor(ps, 2);
      ps += __shfl_xor(ps, 4); ps += __shfl_xor(ps, 8);
      s_run[j] = (need ? s_run[j] * alpha[j] : s_run[j]) + ps;
    }
    if (need) {
#pragma unroll
      for (int f = 0; f < 4; ++f)
#pragma unroll
        for (int j = 0; j < 4; ++j)
          oacc[f][j] *= alpha[j];
    }
#pragma unroll
    for (int f = 0; f < 4; ++f)
#pragma unroll
      for (int j = 0; j < 4; ++j)
        p_s[w][kq * 4 + j][16 * f + fr] = __float2bfloat16(sv[f][j]);
#pragma unroll
    for (int kk = 0; kk < 2; ++kk) {
      bf16x8 pf = *(const bf16x8*)&p_s[w][fr][kq * 8 + 32 * kk];
#pragma unroll
      for (int f = 0; f < 4; ++f) {
        int d = 16 * f + fr;
        int cc = kq * 8 + 32 * kk;
        uint32_t byte = ((uint32_t)d << 7) + 2u * (uint32_t)cc;
        byte ^= (uint32_t)(((d & 7) ^ (d >> 3)) << 4);
        bf16x8 vf = *(const bf16x8*)((char*)vt_s + byte);
        oacc[f] = __builtin_amdgcn_mfma_f32_16x16x32_bf16(pf, vf, oacc[f], 0, 0, 0);
      }
    }
  }

#pragma unroll
  for (int f = 0; f < 4; ++f)
#pragma unroll
    for (int j = 0; j < 4; ++j) {
      int r = 16 * w + kq * 4 + j;
      int d = 16 * f + fr;
      float o = oacc[f][j] / s_run[j];
      Y[(size_t)(b * LL + l0 + r) * DD + h * 64 + d] = __float2bfloat16(o);
    }
}

// ---------------- launch ----------------
extern "C" void kernel_launch(void* const* d_in, const int* in_sizes, int n_in,
                              void* d_out, int out_size, void* d_ws, size_t ws_size,
                              hipStream_t stream) {
  (void)in_sizes; (void)n_in; (void)out_size; (void)ws_size;
  const float* x     = (const float*)d_in[0];
  const float* ln1w  = (const float*)d_in[1];
  const float* ln1b  = (const float*)d_in[2];
  const float* Wqkv  = (const float*)d_in[3];
  const float* bqkv  = (const float*)d_in[4];
  const float* Wproj = (const float*)d_in[5];
  const float* bproj = (const float*)d_in[6];
  const float* Er    = (const float*)d_in[7];
  const float* ln2w  = (const float*)d_in[8];
  const float* ln2b  = (const float*)d_in[9];
  const float* Wfc   = (const float*)d_in[10];
  const float* bfc   = (const float*)d_in[11];
  const float* Wfc2  = (const float*)d_in[12];
  const float* bfc2  = (const float*)d_in[13];
  float* out = (float*)d_out;

  char* ws = (char*)d_ws;
  const size_t MB = 1ull << 20;
  __hip_bfloat16* h1    = (__hip_bfloat16*)(ws + 0);        // 8 MB
  __hip_bfloat16* qkvb  = (__hip_bfloat16*)(ws + 8 * MB);   // 24 MB
  __hip_bfloat16* mbuf  = (__hip_bfloat16*)(ws + 0);        // 32 MB (aliases h1+qkvb)
  __hip_bfloat16* yb    = (__hip_bfloat16*)(ws + 32 * MB);  // 8 MB
  __hip_bfloat16* h2    = (__hip_bfloat16*)(ws + 32 * MB);  // 8 MB (aliases yb)
  float*          x2    = (float*)(ws + 40 * MB);           // 16 MB
  __hip_bfloat16* Wqkvt = (__hip_bfloat16*)(ws + 56 * MB);  // 6 MB
  __hip_bfloat16* Erb   = (__hip_bfloat16*)(ws + 62 * MB);  // 128 KB
  __hip_bfloat16* Wprojt= (__hip_bfloat16*)(ws + 63 * MB);  // 2 MB
  __hip_bfloat16* Wfct  = (__hip_bfloat16*)(ws + 66 * MB);  // 8 MB
  __hip_bfloat16* Wfc2t = (__hip_bfloat16*)(ws + 75 * MB);  // 8 MB

  dim3 blk(256);

  prep_weights<<<dim3(16448), blk, 0, stream>>>(Wqkv, Wproj, Wfc, Wfc2, Er,
                                                x, ln1w, ln1b,
                                                Wqkvt, Wprojt, Wfct, Wfc2t, Erb, h1);

  gemm256x128<0><<<dim3(3072 / 128, 4096 / 256), dim3(512), 0, stream>>>(
      h1, Wqkvt, bqkv, nullptr, qkvb, 4096, 3072, 1024);

  attn_mfma<<<dim3(1024), blk, 0, stream>>>(qkvb, Erb, yb);

  gemm128x64w8<2><<<dim3(1024 / 64, 4096 / 128), dim3(512), 0, stream>>>(
      yb, Wprojt, bproj, x, x2, 4096, 1024, 1024);

  ln_kernel<<<4096, blk, 0, stream>>>(x2, ln2w, ln2b, h2);

  gemm128bk64<1><<<dim3(4096 / 128, 4096 / 128), dim3(512), 0, stream>>>(
      h2, Wfct, bfc, nullptr, mbuf, 4096, 4096, 1024);

  gemm128x64w8<2><<<dim3(1024 / 64, 4096 / 128), dim3(512), 0, stream>>>(
      mbuf, Wfc2t, bfc2, x2, out, 4096, 1024, 4096);
}